// Round 4
// baseline (461.122 us; speedup 1.0000x reference)
//
#include <hip/hip_runtime.h>
#include <hip/hip_bf16.h>
#include <math.h>

// ---------------------------------------------------------------------------
typedef __bf16 bf16_t;
typedef __bf16 bf16x8 __attribute__((ext_vector_type(8)));
typedef __bf16 bf16x2 __attribute__((ext_vector_type(2)));
typedef float  f32x4  __attribute__((ext_vector_type(4)));

#define D_MODEL 512
#define NHEAD   8
#define HD      64
#define D_FF    2048
#define TOKENS  8192   // 4 * 2048
#define SEQ     2048
#define BATCH   4

// async global->LDS, 16B per lane; LDS dest = wave-uniform base + lane*16
__device__ __forceinline__ void gload16(const bf16_t* g, bf16_t* l)
{
    __builtin_amdgcn_global_load_lds(
        (const __attribute__((address_space(1))) void*)g,
        (__attribute__((address_space(3))) void*)l,
        16, 0, 0);
}

__device__ __forceinline__ void cvt4(const float* s, bf16_t* d)
{
    float4 v = *(const float4*)s;
    alignas(8) bf16_t t[4] = {(bf16_t)v.x, (bf16_t)v.y, (bf16_t)v.z, (bf16_t)v.w};
    *(uint2*)d = *(const uint2*)t;
}

// ---------------------------------------------------------------------------
// All weight conversions + bias concat + zero-bias fill in ONE kernel.
// ---------------------------------------------------------------------------
__global__ void cvt_weights(const float* __restrict__ Wq, const float* __restrict__ Wk,
                            const float* __restrict__ Wv, const float* __restrict__ Wo,
                            const float* __restrict__ W1, const float* __restrict__ W2,
                            const float* __restrict__ bq, const float* __restrict__ bk,
                            const float* __restrict__ bv,
                            bf16_t* __restrict__ Wqkvb, bf16_t* __restrict__ Wob,
                            bf16_t* __restrict__ W1b, bf16_t* __restrict__ W2b,
                            float* __restrict__ bqkv, float* __restrict__ zbias)
{
    int i = blockIdx.x * 256 + threadIdx.x;   // one thread = 4 elements
    if (i < 65536)        cvt4(Wq + (size_t)i * 4,            Wqkvb + (size_t)i * 4);
    else if (i < 131072)  cvt4(Wk + (size_t)(i - 65536) * 4,  Wqkvb + (size_t)i * 4);
    else if (i < 196608)  cvt4(Wv + (size_t)(i - 131072) * 4, Wqkvb + (size_t)i * 4);
    else if (i < 262144)  cvt4(Wo + (size_t)(i - 196608) * 4, Wob + (size_t)(i - 196608) * 4);
    else if (i < 524288)  cvt4(W1 + (size_t)(i - 262144) * 4, W1b + (size_t)(i - 262144) * 4);
    else if (i < 786432)  cvt4(W2 + (size_t)(i - 524288) * 4, W2b + (size_t)(i - 524288) * 4);
    else if (i < 786816) {
        int j = i - 786432;   // 0..383 -> 1536 bias floats
        const float* s = (j < 128) ? bq + j * 4 : (j < 256) ? bk + (j - 128) * 4
                                                            : bv + (j - 256) * 4;
        *(float4*)(bqkv + (j & 127) * 4 + (j >> 7) * 512) = *(const float4*)s;
    } else if (i < 786944) {
        int j = i - 786816;   // 0..127 -> 512 zero floats
        *(float4*)(zbias + j * 4) = make_float4(0.f, 0.f, 0.f, 0.f);
    }
}

// ---------------------------------------------------------------------------
// GEMM: C[M,N] = A[M,K] @ B[N,K]^T + bias, bf16 in, fp32 accum.
// BM x 128 tile, BK=32, 256 threads. global_load_lds staging for bf16 A/B;
// AF32: A is fp32 in global, converted during staging (fuses the src cvt).
// SPLIT2: gridDim.z==2, each z-half does K/2 and writes Cout + z*M*N;
//         z==1 uses biasz (zeros) so bias is applied exactly once.
// EPI: 0 = bias->bf16 ; 1 = bias+GELU->bf16 ; 2 = bias->fp32
// ---------------------------------------------------------------------------
template <int BM, int EPI, bool AF32, bool SPLIT2>
__global__ __launch_bounds__(256)
void gemm_bt(const void* __restrict__ Ain, const bf16_t* __restrict__ B,
             const float* __restrict__ bias, const float* __restrict__ biasz,
             void* __restrict__ Cout, int M, int N, int K)
{
    constexpr int MI = BM / 32;
    __shared__ bf16_t sA[BM][32];
    __shared__ bf16_t sB[128][32];
    bf16_t* sAf = &sA[0][0];
    bf16_t* sBf = &sB[0][0];

    const int tid  = threadIdx.x;
    const int wave = tid >> 6;
    const int lane = tid & 63;
    const int g    = lane >> 4;
    const int c16  = lane & 15;
    const int wm   = (wave >> 1) * (BM / 2);
    const int wn   = (wave & 1) * 64;
    const int m0   = blockIdx.y * BM;
    const int n0   = blockIdx.x * 128;

    const int zz    = SPLIT2 ? blockIdx.z : 0;
    const int Keff  = SPLIT2 ? (K >> 1) : K;
    const int kbase = zz * Keff;
    const float* bptr = (SPLIT2 && zz) ? biasz : bias;

    const f32x4 fz = {0.f, 0.f, 0.f, 0.f};
    f32x4 acc[MI][4];
#pragma unroll
    for (int i = 0; i < MI; i++)
#pragma unroll
        for (int j = 0; j < 4; j++) acc[i][j] = fz;

    const int srow = tid >> 2;
    const int scol = (tid & 3) * 8;
    const bf16_t* pa  = AF32 ? nullptr : (const bf16_t*)Ain + (size_t)(m0 + srow) * K + kbase + scol;
    const float*  paf = AF32 ? (const float*)Ain + (size_t)(m0 + srow) * K + kbase + scol : nullptr;
    const bf16_t* pb  = B + (size_t)(n0 + srow) * K + kbase + scol;

    for (int k0 = 0; k0 < Keff; k0 += 32) {
        float4 ua[BM / 64][2];
        if (AF32) {
#pragma unroll
            for (int i = 0; i < BM / 64; i++) {
                ua[i][0] = *(const float4*)(paf + (size_t)i * 64 * K + k0);
                ua[i][1] = *(const float4*)(paf + (size_t)i * 64 * K + k0 + 4);
            }
        }
        __syncthreads();                   // readers of previous tile done
        if (AF32) {
#pragma unroll
            for (int i = 0; i < BM / 64; i++) {
                alignas(16) bf16_t t[8];
#pragma unroll
                for (int j = 0; j < 4; j++) {
                    t[j]     = (bf16_t)((const float*)&ua[i][0])[j];
                    t[j + 4] = (bf16_t)((const float*)&ua[i][1])[j];
                }
                *(int4*)(sAf + i * 2048 + tid * 8) = *(const int4*)t;
            }
        } else {
#pragma unroll
            for (int i = 0; i < BM / 64; i++)
                gload16(pa + (size_t)i * 64 * K + k0, sAf + i * 2048 + tid * 8);
        }
#pragma unroll
        for (int i = 0; i < 2; i++)
            gload16(pb + (size_t)i * 64 * K + k0, sBf + i * 2048 + tid * 8);
        __syncthreads();

        bf16x8 af[MI], bfr[4];
#pragma unroll
        for (int i = 0; i < MI; i++)
            af[i] = *(const bf16x8*)&sA[wm + i * 16 + c16][g * 8];
#pragma unroll
        for (int j = 0; j < 4; j++)
            bfr[j] = *(const bf16x8*)&sB[wn + j * 16 + c16][g * 8];
#pragma unroll
        for (int mi = 0; mi < MI; mi++)
#pragma unroll
            for (int ni = 0; ni < 4; ni++)
                acc[mi][ni] = __builtin_amdgcn_mfma_f32_16x16x32_bf16(
                    af[mi], bfr[ni], acc[mi][ni], 0, 0, 0);
    }

    float* outf = (float*)Cout + (size_t)zz * M * N;
#pragma unroll
    for (int mi = 0; mi < MI; mi++) {
#pragma unroll
        for (int ni = 0; ni < 4; ni++) {
            const int col = n0 + wn + ni * 16 + c16;
            const float bv = bptr[col];
#pragma unroll
            for (int r = 0; r < 4; r++) {
                const int row = m0 + wm + mi * 16 + g * 4 + r;
                float v = acc[mi][ni][r] + bv;
                if (EPI == 1) v = 0.5f * v * (1.f + erff(v * 0.70710678118654752f));
                if (EPI == 2)
                    outf[(size_t)row * N + col] = v;
                else
                    ((bf16_t*)Cout)[(size_t)row * N + col] = (bf16_t)v;
            }
        }
    }
}

// ---------------------------------------------------------------------------
// transpose V out of QKV into Vt[bh][64][2048], t-dim interleaved within each
// 32-chunk: pos = 2*(t%16) + (t/16)%2 (+32*(t/32)). MFMA k-sums are
// permutation-invariant per 32-half, so flash uses this order for V^T and P.
// ---------------------------------------------------------------------------
__global__ __launch_bounds__(256)
void transpose_v(const bf16_t* __restrict__ qkv, bf16_t* __restrict__ vt)
{
    __shared__ bf16_t st[64][72];
    const int t0 = blockIdx.x * 64;
    const int bh = blockIdx.y;
    const int b = bh >> 3, h = bh & 7;
    const int tid = threadIdx.x;

    for (int c = tid; c < 512; c += 256) {
        int r = c >> 3, cj = (c & 7) * 8;
        const bf16_t* src = qkv + ((size_t)(b * SEQ + t0 + r)) * 1536 + 1024 + h * 64 + cj;
        *(int4*)&st[r][cj] = *(const int4*)src;
    }
    __syncthreads();
    for (int c = tid; c < 512; c += 256) {
        int d = c >> 3, pj = (c & 7) * 8;
        alignas(16) bf16_t tmp[8];
#pragma unroll
        for (int j = 0; j < 8; j++) {
            int p = pj + j;
            int t = (p & 32) + ((p & 1) << 4) + ((p & 31) >> 1);   // inverse perm
            tmp[j] = st[t][d];
        }
        *(int4*)(vt + ((size_t)(bh * 64 + d)) * SEQ + t0 + pj) = *(const int4*)tmp;
    }
}

// ---------------------------------------------------------------------------
// Flash attention v4. grid (SEQ/64, B*H) = (32,32), block 128 (2 waves x
// 32 q-rows). Single-buffered K/V (30 KB LDS -> 4 blocks/CU = 4 independent
// barrier domains/CU). Next K/V tile prefetched to registers, written to LDS
// after the read-barrier -> global latency overlaps compute. Q pre-scaled by
// (1/8)*log2(e) so P = exp2(S). Row-sum l via ones column in V^T (nd=4).
// ---------------------------------------------------------------------------
__global__ __launch_bounds__(128)
void flash_attn(const bf16_t* __restrict__ qkv, const bf16_t* __restrict__ vt,
                bf16_t* __restrict__ ctx)
{
    __shared__ bf16_t sK[64][72];    // 9 KB
    __shared__ bf16_t sVt[80][72];   // 11.25 KB ; rows 64..79: ones row + zeros
    __shared__ bf16_t sP[64][72];    // 9 KB

    const int bh = blockIdx.y;
    const int b = bh >> 3, h = bh & 7;
    const int q0 = blockIdx.x * 64;
    const int tid = threadIdx.x;
    const int wave = tid >> 6, lane = tid & 63;
    const int g = lane >> 4, c16 = lane & 15;

    // ones rows (never touched by staging)
    for (int c = tid; c < 16 * 72; c += 128)
        sVt[64 + c / 72][c % 72] = (c / 72 == 0) ? (bf16_t)1.0f : (bf16_t)0.0f;

    const float qscale = 0.125f * 1.4426950408889634f;   // 1/sqrt(64) * log2(e)
    bf16x8 aq[2][2];
#pragma unroll
    for (int mf = 0; mf < 2; mf++)
#pragma unroll
        for (int ks = 0; ks < 2; ks++) {
            bf16x8 v = *(const bf16x8*)(qkv +
                ((size_t)(b * SEQ + q0 + wave * 32 + mf * 16 + c16)) * 1536 +
                h * 64 + ks * 32 + g * 8);
#pragma unroll
            for (int j = 0; j < 8; j++) v[j] = (bf16_t)((float)v[j] * qscale);
            aq[mf][ks] = v;
        }

    const f32x4 fz = {0.f, 0.f, 0.f, 0.f};
    f32x4 acc_o[2][5];
#pragma unroll
    for (int mf = 0; mf < 2; mf++)
#pragma unroll
        for (int nd = 0; nd < 5; nd++) acc_o[mf][nd] = fz;

    // staging map: 4 rounds; round j -> row j*16 + (tid>>3), col chunk (tid&7)*8
    const int srow = tid >> 3;
    const int scol = (tid & 7) * 8;
    const bf16_t* pk = qkv + ((size_t)(b * SEQ) + srow) * 1536 + 512 + h * 64 + scol;
    const bf16_t* pv = vt + ((size_t)(bh * 64) + srow) * SEQ + scol;

    int4 rK[4], rV[4];
#pragma unroll
    for (int j = 0; j < 4; j++) {           // preload tile 0
        rK[j] = *(const int4*)(pk + (size_t)(j * 16) * 1536);
        rV[j] = *(const int4*)(pv + (size_t)(j * 16) * SEQ);
    }

    for (int it = 0; it < 32; ++it) {
        __syncthreads();   // both waves done reading previous tile
#pragma unroll
        for (int j = 0; j < 4; j++) {
            *(int4*)&sK[j * 16 + srow][scol]  = rK[j];
            *(int4*)&sVt[j * 16 + srow][scol] = rV[j];
        }
        const size_t kvn = (it < 31) ? (size_t)(it + 1) * 64 : (size_t)31 * 64;
#pragma unroll
        for (int j = 0; j < 4; j++) {       // prefetch next tile (overlaps compute)
            rK[j] = *(const int4*)(pk + (kvn + j * 16) * 1536);
            rV[j] = *(const int4*)(pv + kvn + (size_t)(j * 16) * SEQ);
        }
        __syncthreads();   // staged tile visible

        // S = (Q*qscale) K^T
        f32x4 accs[2][4];
#pragma unroll
        for (int mf = 0; mf < 2; mf++)
#pragma unroll
            for (int n = 0; n < 4; n++) accs[mf][n] = fz;
#pragma unroll
        for (int ks = 0; ks < 2; ks++)
#pragma unroll
            for (int n = 0; n < 4; n++) {
                bf16x8 bk = *(const bf16x8*)&sK[n * 16 + c16][ks * 32 + g * 8];
                accs[0][n] = __builtin_amdgcn_mfma_f32_16x16x32_bf16(aq[0][ks], bk, accs[0][n], 0, 0, 0);
                accs[1][n] = __builtin_amdgcn_mfma_f32_16x16x32_bf16(aq[1][ks], bk, accs[1][n], 0, 0, 0);
            }

        // P = 2^S, packed-pair stores in interleaved-t order (conflict-free)
#pragma unroll
        for (int mf = 0; mf < 2; mf++)
#pragma unroll
            for (int r = 0; r < 4; r++) {
                const int prow = wave * 32 + mf * 16 + g * 4 + r;
#pragma unroll
                for (int ks = 0; ks < 2; ks++) {
                    bf16x2 pp;
                    pp[0] = (bf16_t)__builtin_amdgcn_exp2f(accs[mf][2 * ks][r]);
                    pp[1] = (bf16_t)__builtin_amdgcn_exp2f(accs[mf][2 * ks + 1][r]);
                    *(bf16x2*)&sP[prow][ks * 32 + 2 * c16] = pp;
                }
            }

        // O += P @ [V | 1]  (sP rows wave-private; DS ops in-order per wave)
#pragma unroll
        for (int ks = 0; ks < 2; ks++) {
            bf16x8 ap0 = *(const bf16x8*)&sP[wave * 32 + c16][ks * 32 + g * 8];
            bf16x8 ap1 = *(const bf16x8*)&sP[wave * 32 + 16 + c16][ks * 32 + g * 8];
#pragma unroll
            for (int nd = 0; nd < 5; nd++) {
                bf16x8 vb = *(const bf16x8*)&sVt[nd * 16 + c16][ks * 32 + g * 8];
                acc_o[0][nd] = __builtin_amdgcn_mfma_f32_16x16x32_bf16(ap0, vb, acc_o[0][nd], 0, 0, 0);
                acc_o[1][nd] = __builtin_amdgcn_mfma_f32_16x16x32_bf16(ap1, vb, acc_o[1][nd], 0, 0, 0);
            }
        }
    }

    // epilogue: divide by l (ones-column sum sits at c16==0 lane of each group)
#pragma unroll
    for (int mf = 0; mf < 2; mf++)
#pragma unroll
        for (int r = 0; r < 4; r++) {
            float lv  = __shfl(acc_o[mf][4][r], lane & 48, 64);
            float inv = 1.0f / lv;
            const size_t base =
                ((size_t)(b * SEQ + q0 + wave * 32 + mf * 16 + g * 4 + r)) * 512 + h * 64;
#pragma unroll
            for (int nd = 0; nd < 4; nd++)
                ctx[base + nd * 16 + c16] = (bf16_t)(acc_o[mf][nd][r] * inv);
        }
}

// ---------------------------------------------------------------------------
// out = LayerNorm(a + b + c) * gamma + beta ; optional bf16 copy
// ---------------------------------------------------------------------------
__global__ __launch_bounds__(256)
void add_ln3(const float* __restrict__ a, const float* __restrict__ b,
             const float* __restrict__ c,
             const float* __restrict__ gamma, const float* __restrict__ beta,
             float* __restrict__ outf, bf16_t* __restrict__ outb)
{
    const int row  = blockIdx.x * 4 + (threadIdx.x >> 6);
    const int lane = threadIdx.x & 63;
    const size_t base = (size_t)row * 512 + lane * 8;

    float v[8];
#pragma unroll
    for (int h = 0; h < 2; h++) {
        float4 av = *(const float4*)(a + base + h * 4);
        float4 bv = *(const float4*)(b + base + h * 4);
        float4 cv = *(const float4*)(c + base + h * 4);
        v[h * 4 + 0] = av.x + bv.x + cv.x;
        v[h * 4 + 1] = av.y + bv.y + cv.y;
        v[h * 4 + 2] = av.z + bv.z + cv.z;
        v[h * 4 + 3] = av.w + bv.w + cv.w;
    }

    float s = 0.f;
#pragma unroll
    for (int i = 0; i < 8; i++) s += v[i];
#pragma unroll
    for (int off = 32; off > 0; off >>= 1) s += __shfl_xor(s, off);
    const float mu = s * (1.f / 512.f);

    float q = 0.f;
#pragma unroll
    for (int i = 0; i < 8; i++) { float d = v[i] - mu; q += d * d; }
#pragma unroll
    for (int off = 32; off > 0; off >>= 1) q += __shfl_xor(q, off);
    const float rstd = rsqrtf(q * (1.f / 512.f) + 1e-5f);

    float4 g0 = *(const float4*)(gamma + lane * 8);
    float4 g1 = *(const float4*)(gamma + lane * 8 + 4);
    float4 e0 = *(const float4*)(beta + lane * 8);
    float4 e1 = *(const float4*)(beta + lane * 8 + 4);
    const float gg[8] = {g0.x, g0.y, g0.z, g0.w, g1.x, g1.y, g1.z, g1.w};
    const float ee[8] = {e0.x, e0.y, e0.z, e0.w, e1.x, e1.y, e1.z, e1.w};

    float o[8];
#pragma unroll
    for (int i = 0; i < 8; i++) o[i] = (v[i] - mu) * rstd * gg[i] + ee[i];

    *(float4*)(outf + base)     = make_float4(o[0], o[1], o[2], o[3]);
    *(float4*)(outf + base + 4) = make_float4(o[4], o[5], o[6], o[7]);
    if (outb) {
        alignas(16) bf16_t ob[8];
#pragma unroll
        for (int i = 0; i < 8; i++) ob[i] = (bf16_t)o[i];
        *(int4*)(outb + base) = *(const int4*)ob;
    }
}

// ---------------------------------------------------------------------------
extern "C" void kernel_launch(void* const* d_in, const int* in_sizes, int n_in,
                              void* d_out, int out_size, void* d_ws, size_t ws_size,
                              hipStream_t stream)
{
    const float* src = (const float*)d_in[0];
    const float* Wq  = (const float*)d_in[1];  const float* bq  = (const float*)d_in[2];
    const float* Wk  = (const float*)d_in[3];  const float* bk  = (const float*)d_in[4];
    const float* Wv  = (const float*)d_in[5];  const float* bv  = (const float*)d_in[6];
    const float* Wo  = (const float*)d_in[7];  const float* bo  = (const float*)d_in[8];
    const float* W1  = (const float*)d_in[9];  const float* b1  = (const float*)d_in[10];
    const float* W2  = (const float*)d_in[11]; const float* b2  = (const float*)d_in[12];
    const float* g1  = (const float*)d_in[13]; const float* be1 = (const float*)d_in[14];
    const float* g2  = (const float*)d_in[15]; const float* be2 = (const float*)d_in[16];
    float* out = (float*)d_out;

    char* ws = (char*)d_ws;
    size_t off = 0;
    auto alloc = [&](size_t bytes) -> void* {
        void* p = ws + off;
        off = (off + bytes + 255) & ~(size_t)255;
        return p;
    };

    bf16_t* Wqkvb = (bf16_t*)alloc((size_t)1536 * 512 * 2);
    bf16_t* Wob   = (bf16_t*)alloc((size_t)512 * 512 * 2);
    bf16_t* W1b   = (bf16_t*)alloc((size_t)2048 * 512 * 2);
    bf16_t* W2b   = (bf16_t*)alloc((size_t)512 * 2048 * 2);
    float*  bqkv  = (float*)alloc(1536 * 4);
    float*  zbias = (float*)alloc(512 * 4);
    bf16_t* QKV   = (bf16_t*)alloc((size_t)TOKENS * 1536 * 2);  // contiguous with Vt
    bf16_t* Vt    = (bf16_t*)alloc((size_t)32 * 64 * SEQ * 2);
    bf16_t* CTX   = (bf16_t*)alloc((size_t)TOKENS * 512 * 2);
    float*  ATTa  = (float*)alloc((size_t)TOKENS * 512 * 4);    // contiguous with ATTb
    float*  ATTb  = (float*)alloc((size_t)TOKENS * 512 * 4);
    float*  X1    = (float*)alloc((size_t)TOKENS * 512 * 4);
    bf16_t* X1b   = (bf16_t*)alloc((size_t)TOKENS * 512 * 2);

    bf16_t* H    = QKV;    // alias: QKV+Vt (33.55 MB exactly) dead after flash
    float*  FFNa = ATTa;   // alias: ATTa/ATTb dead after ln1 (contiguous pair)
    float*  FFNb = ATTb;

    cvt_weights<<<3074, 256, 0, stream>>>(Wq, Wk, Wv, Wo, W1, W2, bq, bk, bv,
                                          Wqkvb, Wob, W1b, W2b, bqkv, zbias);

    // fused QKV projection, fp32 A staged+converted in-kernel
    gemm_bt<128, 0, true, false><<<dim3(12, 64), 256, 0, stream>>>(
        src, Wqkvb, bqkv, zbias, QKV, TOKENS, 1536, 512);

    transpose_v<<<dim3(32, 32), 256, 0, stream>>>(QKV, Vt);
    flash_attn<<<dim3(32, 32), 128, 0, stream>>>(QKV, Vt, CTX);

    // Wo projection, split-K=2 -> ATTa/ATTb partials
    gemm_bt<64, 2, false, true><<<dim3(4, 128, 2), 256, 0, stream>>>(
        CTX, Wob, bo, zbias, ATTa, TOKENS, 512, 512);

    add_ln3<<<2048, 256, 0, stream>>>(src, ATTa, ATTb, g1, be1, X1, X1b);

    gemm_bt<128, 1, false, false><<<dim3(16, 64), 256, 0, stream>>>(
        X1b, W1b, b1, zbias, H, TOKENS, 2048, 512);

    // W2, split-K=2 -> FFNa/FFNb partials
    gemm_bt<64, 2, false, true><<<dim3(4, 128, 2), 256, 0, stream>>>(
        H, W2b, b2, zbias, FFNa, TOKENS, 512, 2048);

    add_ln3<<<2048, 256, 0, stream>>>(X1, FFNa, FFNb, g2, be2, out, nullptr);
}

// Round 5
// 399.095 us; speedup vs baseline: 1.1554x; 1.1554x over previous
//
#include <hip/hip_runtime.h>
#include <hip/hip_bf16.h>
#include <math.h>

// ---------------------------------------------------------------------------
typedef __bf16 bf16_t;
typedef __bf16 bf16x8 __attribute__((ext_vector_type(8)));
typedef __bf16 bf16x2 __attribute__((ext_vector_type(2)));
typedef float  f32x4  __attribute__((ext_vector_type(4)));

#define D_MODEL 512
#define NHEAD   8
#define HD      64
#define D_FF    2048
#define TOKENS  8192   // 4 * 2048
#define SEQ     2048
#define BATCH   4

// async global->LDS, 16B per lane; LDS dest = wave-uniform base + lane*16
__device__ __forceinline__ void gload16(const bf16_t* g, bf16_t* l)
{
    __builtin_amdgcn_global_load_lds(
        (const __attribute__((address_space(1))) void*)g,
        (__attribute__((address_space(3))) void*)l,
        16, 0, 0);
}

__device__ __forceinline__ void cvt4(const float* s, bf16_t* d)
{
    float4 v = *(const float4*)s;
    alignas(8) bf16_t t[4] = {(bf16_t)v.x, (bf16_t)v.y, (bf16_t)v.z, (bf16_t)v.w};
    *(uint2*)d = *(const uint2*)t;
}

// ---------------------------------------------------------------------------
// All weight conversions + bias concat + zero-bias fill in ONE kernel.
// ---------------------------------------------------------------------------
__global__ void cvt_weights(const float* __restrict__ Wq, const float* __restrict__ Wk,
                            const float* __restrict__ Wv, const float* __restrict__ Wo,
                            const float* __restrict__ W1, const float* __restrict__ W2,
                            const float* __restrict__ bq, const float* __restrict__ bk,
                            const float* __restrict__ bv,
                            bf16_t* __restrict__ Wqkvb, bf16_t* __restrict__ Wob,
                            bf16_t* __restrict__ W1b, bf16_t* __restrict__ W2b,
                            float* __restrict__ bqkv, float* __restrict__ zbias)
{
    int i = blockIdx.x * 256 + threadIdx.x;   // one thread = 4 elements
    if (i < 65536)        cvt4(Wq + (size_t)i * 4,            Wqkvb + (size_t)i * 4);
    else if (i < 131072)  cvt4(Wk + (size_t)(i - 65536) * 4,  Wqkvb + (size_t)i * 4);
    else if (i < 196608)  cvt4(Wv + (size_t)(i - 131072) * 4, Wqkvb + (size_t)i * 4);
    else if (i < 262144)  cvt4(Wo + (size_t)(i - 196608) * 4, Wob + (size_t)(i - 196608) * 4);
    else if (i < 524288)  cvt4(W1 + (size_t)(i - 262144) * 4, W1b + (size_t)(i - 262144) * 4);
    else if (i < 786432)  cvt4(W2 + (size_t)(i - 524288) * 4, W2b + (size_t)(i - 524288) * 4);
    else if (i < 786816) {
        int j = i - 786432;   // 0..383 -> 1536 bias floats
        const float* s = (j < 128) ? bq + j * 4 : (j < 256) ? bk + (j - 128) * 4
                                                            : bv + (j - 256) * 4;
        *(float4*)(bqkv + (j & 127) * 4 + (j >> 7) * 512) = *(const float4*)s;
    } else if (i < 786944) {
        int j = i - 786816;   // 0..127 -> 512 zero floats
        *(float4*)(zbias + j * 4) = make_float4(0.f, 0.f, 0.f, 0.f);
    }
}

// ---------------------------------------------------------------------------
// GEMM: C[M,N] = A[M,K] @ B[N,K]^T + bias, bf16 in, fp32 accum.
// BM x 128 tile, BK=32, 256 threads. global_load_lds staging for bf16 A/B;
// AF32: A is fp32 in global, converted during staging (fuses the src cvt).
// SPLIT2: gridDim.z==2, each z-half does K/2 and writes Cout + z*M*N;
//         z==1 uses biasz (zeros) so bias is applied exactly once.
// EPI: 0 = bias->bf16 ; 1 = bias+GELU->bf16 ; 2 = bias->fp32
// ---------------------------------------------------------------------------
template <int BM, int EPI, bool AF32, bool SPLIT2>
__global__ __launch_bounds__(256)
void gemm_bt(const void* __restrict__ Ain, const bf16_t* __restrict__ B,
             const float* __restrict__ bias, const float* __restrict__ biasz,
             void* __restrict__ Cout, int M, int N, int K)
{
    constexpr int MI = BM / 32;
    __shared__ bf16_t sA[BM][32];
    __shared__ bf16_t sB[128][32];
    bf16_t* sAf = &sA[0][0];
    bf16_t* sBf = &sB[0][0];

    const int tid  = threadIdx.x;
    const int wave = tid >> 6;
    const int lane = tid & 63;
    const int g    = lane >> 4;
    const int c16  = lane & 15;
    const int wm   = (wave >> 1) * (BM / 2);
    const int wn   = (wave & 1) * 64;
    const int m0   = blockIdx.y * BM;
    const int n0   = blockIdx.x * 128;

    const int zz    = SPLIT2 ? blockIdx.z : 0;
    const int Keff  = SPLIT2 ? (K >> 1) : K;
    const int kbase = zz * Keff;
    const float* bptr = (SPLIT2 && zz) ? biasz : bias;

    const f32x4 fz = {0.f, 0.f, 0.f, 0.f};
    f32x4 acc[MI][4];
#pragma unroll
    for (int i = 0; i < MI; i++)
#pragma unroll
        for (int j = 0; j < 4; j++) acc[i][j] = fz;

    const int srow = tid >> 2;
    const int scol = (tid & 3) * 8;
    const bf16_t* pa  = AF32 ? nullptr : (const bf16_t*)Ain + (size_t)(m0 + srow) * K + kbase + scol;
    const float*  paf = AF32 ? (const float*)Ain + (size_t)(m0 + srow) * K + kbase + scol : nullptr;
    const bf16_t* pb  = B + (size_t)(n0 + srow) * K + kbase + scol;

    for (int k0 = 0; k0 < Keff; k0 += 32) {
        float4 ua[BM / 64][2];
        if (AF32) {
#pragma unroll
            for (int i = 0; i < BM / 64; i++) {
                ua[i][0] = *(const float4*)(paf + (size_t)i * 64 * K + k0);
                ua[i][1] = *(const float4*)(paf + (size_t)i * 64 * K + k0 + 4);
            }
        }
        __syncthreads();                   // readers of previous tile done
        if (AF32) {
#pragma unroll
            for (int i = 0; i < BM / 64; i++) {
                alignas(16) bf16_t t[8];
#pragma unroll
                for (int j = 0; j < 4; j++) {
                    t[j]     = (bf16_t)((const float*)&ua[i][0])[j];
                    t[j + 4] = (bf16_t)((const float*)&ua[i][1])[j];
                }
                *(int4*)(sAf + i * 2048 + tid * 8) = *(const int4*)t;
            }
        } else {
#pragma unroll
            for (int i = 0; i < BM / 64; i++)
                gload16(pa + (size_t)i * 64 * K + k0, sAf + i * 2048 + tid * 8);
        }
#pragma unroll
        for (int i = 0; i < 2; i++)
            gload16(pb + (size_t)i * 64 * K + k0, sBf + i * 2048 + tid * 8);
        __syncthreads();

        bf16x8 af[MI], bfr[4];
#pragma unroll
        for (int i = 0; i < MI; i++)
            af[i] = *(const bf16x8*)&sA[wm + i * 16 + c16][g * 8];
#pragma unroll
        for (int j = 0; j < 4; j++)
            bfr[j] = *(const bf16x8*)&sB[wn + j * 16 + c16][g * 8];
#pragma unroll
        for (int mi = 0; mi < MI; mi++)
#pragma unroll
            for (int ni = 0; ni < 4; ni++)
                acc[mi][ni] = __builtin_amdgcn_mfma_f32_16x16x32_bf16(
                    af[mi], bfr[ni], acc[mi][ni], 0, 0, 0);
    }

    float* outf = (float*)Cout + (size_t)zz * M * N;
#pragma unroll
    for (int mi = 0; mi < MI; mi++) {
#pragma unroll
        for (int ni = 0; ni < 4; ni++) {
            const int col = n0 + wn + ni * 16 + c16;
            const float bv = bptr[col];
#pragma unroll
            for (int r = 0; r < 4; r++) {
                const int row = m0 + wm + mi * 16 + g * 4 + r;
                float v = acc[mi][ni][r] + bv;
                if (EPI == 1) v = 0.5f * v * (1.f + erff(v * 0.70710678118654752f));
                if (EPI == 2)
                    outf[(size_t)row * N + col] = v;
                else
                    ((bf16_t*)Cout)[(size_t)row * N + col] = (bf16_t)v;
            }
        }
    }
}

// ---------------------------------------------------------------------------
// transpose V out of QKV into Vt[bh][64][2048], t-dim interleaved within each
// 32-chunk: pos = 2*(t%16) + (t/16)%2 (+32*(t/32)). MFMA k-sums are
// permutation-invariant per 32-half, so flash uses this order for V^T and P.
// ---------------------------------------------------------------------------
__global__ __launch_bounds__(256)
void transpose_v(const bf16_t* __restrict__ qkv, bf16_t* __restrict__ vt)
{
    __shared__ bf16_t st[64][72];
    const int t0 = blockIdx.x * 64;
    const int bh = blockIdx.y;
    const int b = bh >> 3, h = bh & 7;
    const int tid = threadIdx.x;

    for (int c = tid; c < 512; c += 256) {
        int r = c >> 3, cj = (c & 7) * 8;
        const bf16_t* src = qkv + ((size_t)(b * SEQ + t0 + r)) * 1536 + 1024 + h * 64 + cj;
        *(int4*)&st[r][cj] = *(const int4*)src;
    }
    __syncthreads();
    for (int c = tid; c < 512; c += 256) {
        int d = c >> 3, pj = (c & 7) * 8;
        alignas(16) bf16_t tmp[8];
#pragma unroll
        for (int j = 0; j < 8; j++) {
            int p = pj + j;
            int t = (p & 32) + ((p & 1) << 4) + ((p & 31) >> 1);   // inverse perm
            tmp[j] = st[t][d];
        }
        *(int4*)(vt + ((size_t)(bh * 64 + d)) * SEQ + t0 + pj) = *(const int4*)tmp;
    }
}

// ---------------------------------------------------------------------------
// Flash attention v5 = v4 structure with the register-spill fixed.
// grid (SEQ/64, B*H) = (32,32), block 128 (2 waves x 32 q-rows).
// Single-buffered K/V (30 KB LDS -> 4 blocks/CU = 4 independent barrier
// domains/CU). Next K/V tile prefetched to registers, written to LDS after
// the read-barrier -> global latency overlaps compute.
// __launch_bounds__(128, 2): 2 waves/EU = 8 waves/CU target -> 256-VGPR
// budget, so the rK/rV prefetch (32 VGPRs) stays in registers. R4's default
// heuristic capped at 80 VGPRs and spilled 0.5 GB/dispatch to scratch
// (WRITE_SIZE 433 MB, dur 222 us).
// ---------------------------------------------------------------------------
__global__ __launch_bounds__(128, 2)
void flash_attn(const bf16_t* __restrict__ qkv, const bf16_t* __restrict__ vt,
                bf16_t* __restrict__ ctx)
{
    __shared__ bf16_t sK[64][72];    // 9 KB
    __shared__ bf16_t sVt[80][72];   // 11.25 KB ; rows 64..79: ones row + zeros
    __shared__ bf16_t sP[64][72];    // 9 KB

    const int bh = blockIdx.y;
    const int b = bh >> 3, h = bh & 7;
    const int q0 = blockIdx.x * 64;
    const int tid = threadIdx.x;
    const int wave = tid >> 6, lane = tid & 63;
    const int g = lane >> 4, c16 = lane & 15;

    // ones rows (never touched by staging)
    for (int c = tid; c < 16 * 72; c += 128)
        sVt[64 + c / 72][c % 72] = (c / 72 == 0) ? (bf16_t)1.0f : (bf16_t)0.0f;

    const float qscale = 0.125f * 1.4426950408889634f;   // 1/sqrt(64) * log2(e)
    bf16x8 aq[2][2];
#pragma unroll
    for (int mf = 0; mf < 2; mf++)
#pragma unroll
        for (int ks = 0; ks < 2; ks++) {
            bf16x8 v = *(const bf16x8*)(qkv +
                ((size_t)(b * SEQ + q0 + wave * 32 + mf * 16 + c16)) * 1536 +
                h * 64 + ks * 32 + g * 8);
#pragma unroll
            for (int j = 0; j < 8; j++) v[j] = (bf16_t)((float)v[j] * qscale);
            aq[mf][ks] = v;
        }

    const f32x4 fz = {0.f, 0.f, 0.f, 0.f};
    f32x4 acc_o[2][5];
#pragma unroll
    for (int mf = 0; mf < 2; mf++)
#pragma unroll
        for (int nd = 0; nd < 5; nd++) acc_o[mf][nd] = fz;

    // staging map: 4 rounds; round j -> row j*16 + (tid>>3), col chunk (tid&7)*8
    const int srow = tid >> 3;
    const int scol = (tid & 7) * 8;
    const bf16_t* pk = qkv + ((size_t)(b * SEQ) + srow) * 1536 + 512 + h * 64 + scol;
    const bf16_t* pv = vt + ((size_t)(bh * 64) + srow) * SEQ + scol;

    int4 rK[4], rV[4];
#pragma unroll
    for (int j = 0; j < 4; j++) {           // preload tile 0
        rK[j] = *(const int4*)(pk + (size_t)(j * 16) * 1536);
        rV[j] = *(const int4*)(pv + (size_t)(j * 16) * SEQ);
    }

    for (int it = 0; it < 32; ++it) {
        __syncthreads();   // both waves done reading previous tile
#pragma unroll
        for (int j = 0; j < 4; j++) {
            *(int4*)&sK[j * 16 + srow][scol]  = rK[j];
            *(int4*)&sVt[j * 16 + srow][scol] = rV[j];
        }
        const size_t kvn = (it < 31) ? (size_t)(it + 1) * 64 : (size_t)31 * 64;
#pragma unroll
        for (int j = 0; j < 4; j++) {       // prefetch next tile (overlaps compute)
            rK[j] = *(const int4*)(pk + (kvn + j * 16) * 1536);
            rV[j] = *(const int4*)(pv + kvn + (size_t)(j * 16) * SEQ);
        }
        __syncthreads();   // staged tile visible

        // S = (Q*qscale) K^T
        f32x4 accs[2][4];
#pragma unroll
        for (int mf = 0; mf < 2; mf++)
#pragma unroll
            for (int n = 0; n < 4; n++) accs[mf][n] = fz;
#pragma unroll
        for (int ks = 0; ks < 2; ks++)
#pragma unroll
            for (int n = 0; n < 4; n++) {
                bf16x8 bk = *(const bf16x8*)&sK[n * 16 + c16][ks * 32 + g * 8];
                accs[0][n] = __builtin_amdgcn_mfma_f32_16x16x32_bf16(aq[0][ks], bk, accs[0][n], 0, 0, 0);
                accs[1][n] = __builtin_amdgcn_mfma_f32_16x16x32_bf16(aq[1][ks], bk, accs[1][n], 0, 0, 0);
            }

        // P = 2^S, packed-pair stores in interleaved-t order (conflict-free)
#pragma unroll
        for (int mf = 0; mf < 2; mf++)
#pragma unroll
            for (int r = 0; r < 4; r++) {
                const int prow = wave * 32 + mf * 16 + g * 4 + r;
#pragma unroll
                for (int ks = 0; ks < 2; ks++) {
                    bf16x2 pp;
                    pp[0] = (bf16_t)__builtin_amdgcn_exp2f(accs[mf][2 * ks][r]);
                    pp[1] = (bf16_t)__builtin_amdgcn_exp2f(accs[mf][2 * ks + 1][r]);
                    *(bf16x2*)&sP[prow][ks * 32 + 2 * c16] = pp;
                }
            }

        // O += P @ [V | 1]  (sP rows wave-private; DS ops in-order per wave)
#pragma unroll
        for (int ks = 0; ks < 2; ks++) {
            bf16x8 ap0 = *(const bf16x8*)&sP[wave * 32 + c16][ks * 32 + g * 8];
            bf16x8 ap1 = *(const bf16x8*)&sP[wave * 32 + 16 + c16][ks * 32 + g * 8];
#pragma unroll
            for (int nd = 0; nd < 5; nd++) {
                bf16x8 vb = *(const bf16x8*)&sVt[nd * 16 + c16][ks * 32 + g * 8];
                acc_o[0][nd] = __builtin_amdgcn_mfma_f32_16x16x32_bf16(ap0, vb, acc_o[0][nd], 0, 0, 0);
                acc_o[1][nd] = __builtin_amdgcn_mfma_f32_16x16x32_bf16(ap1, vb, acc_o[1][nd], 0, 0, 0);
            }
        }
    }

    // epilogue: divide by l (ones-column sum sits at c16==0 lane of each group)
#pragma unroll
    for (int mf = 0; mf < 2; mf++)
#pragma unroll
        for (int r = 0; r < 4; r++) {
            float lv  = __shfl(acc_o[mf][4][r], lane & 48, 64);
            float inv = 1.0f / lv;
            const size_t base =
                ((size_t)(b * SEQ + q0 + wave * 32 + mf * 16 + g * 4 + r)) * 512 + h * 64;
#pragma unroll
            for (int nd = 0; nd < 4; nd++)
                ctx[base + nd * 16 + c16] = (bf16_t)(acc_o[mf][nd][r] * inv);
        }
}

// ---------------------------------------------------------------------------
// out = LayerNorm(a + b + c) * gamma + beta ; optional bf16 copy
// ---------------------------------------------------------------------------
__global__ __launch_bounds__(256)
void add_ln3(const float* __restrict__ a, const float* __restrict__ b,
             const float* __restrict__ c,
             const float* __restrict__ gamma, const float* __restrict__ beta,
             float* __restrict__ outf, bf16_t* __restrict__ outb)
{
    const int row  = blockIdx.x * 4 + (threadIdx.x >> 6);
    const int lane = threadIdx.x & 63;
    const size_t base = (size_t)row * 512 + lane * 8;

    float v[8];
#pragma unroll
    for (int h = 0; h < 2; h++) {
        float4 av = *(const float4*)(a + base + h * 4);
        float4 bv = *(const float4*)(b + base + h * 4);
        float4 cv = *(const float4*)(c + base + h * 4);
        v[h * 4 + 0] = av.x + bv.x + cv.x;
        v[h * 4 + 1] = av.y + bv.y + cv.y;
        v[h * 4 + 2] = av.z + bv.z + cv.z;
        v[h * 4 + 3] = av.w + bv.w + cv.w;
    }

    float s = 0.f;
#pragma unroll
    for (int i = 0; i < 8; i++) s += v[i];
#pragma unroll
    for (int off = 32; off > 0; off >>= 1) s += __shfl_xor(s, off);
    const float mu = s * (1.f / 512.f);

    float q = 0.f;
#pragma unroll
    for (int i = 0; i < 8; i++) { float d = v[i] - mu; q += d * d; }
#pragma unroll
    for (int off = 32; off > 0; off >>= 1) q += __shfl_xor(q, off);
    const float rstd = rsqrtf(q * (1.f / 512.f) + 1e-5f);

    float4 g0 = *(const float4*)(gamma + lane * 8);
    float4 g1 = *(const float4*)(gamma + lane * 8 + 4);
    float4 e0 = *(const float4*)(beta + lane * 8);
    float4 e1 = *(const float4*)(beta + lane * 8 + 4);
    const float gg[8] = {g0.x, g0.y, g0.z, g0.w, g1.x, g1.y, g1.z, g1.w};
    const float ee[8] = {e0.x, e0.y, e0.z, e0.w, e1.x, e1.y, e1.z, e1.w};

    float o[8];
#pragma unroll
    for (int i = 0; i < 8; i++) o[i] = (v[i] - mu) * rstd * gg[i] + ee[i];

    *(float4*)(outf + base)     = make_float4(o[0], o[1], o[2], o[3]);
    *(float4*)(outf + base + 4) = make_float4(o[4], o[5], o[6], o[7]);
    if (outb) {
        alignas(16) bf16_t ob[8];
#pragma unroll
        for (int i = 0; i < 8; i++) ob[i] = (bf16_t)o[i];
        *(int4*)(outb + base) = *(const int4*)ob;
    }
}

// ---------------------------------------------------------------------------
extern "C" void kernel_launch(void* const* d_in, const int* in_sizes, int n_in,
                              void* d_out, int out_size, void* d_ws, size_t ws_size,
                              hipStream_t stream)
{
    const float* src = (const float*)d_in[0];
    const float* Wq  = (const float*)d_in[1];  const float* bq  = (const float*)d_in[2];
    const float* Wk  = (const float*)d_in[3];  const float* bk  = (const float*)d_in[4];
    const float* Wv  = (const float*)d_in[5];  const float* bv  = (const float*)d_in[6];
    const float* Wo  = (const float*)d_in[7];  const float* bo  = (const float*)d_in[8];
    const float* W1  = (const float*)d_in[9];  const float* b1  = (const float*)d_in[10];
    const float* W2  = (const float*)d_in[11]; const float* b2  = (const float*)d_in[12];
    const float* g1  = (const float*)d_in[13]; const float* be1 = (const float*)d_in[14];
    const float* g2  = (const float*)d_in[15]; const float* be2 = (const float*)d_in[16];
    float* out = (float*)d_out;

    char* ws = (char*)d_ws;
    size_t off = 0;
    auto alloc = [&](size_t bytes) -> void* {
        void* p = ws + off;
        off = (off + bytes + 255) & ~(size_t)255;
        return p;
    };

    bf16_t* Wqkvb = (bf16_t*)alloc((size_t)1536 * 512 * 2);
    bf16_t* Wob   = (bf16_t*)alloc((size_t)512 * 512 * 2);
    bf16_t* W1b   = (bf16_t*)alloc((size_t)2048 * 512 * 2);
    bf16_t* W2b   = (bf16_t*)alloc((size_t)512 * 2048 * 2);
    float*  bqkv  = (float*)alloc(1536 * 4);
    float*  zbias = (float*)alloc(512 * 4);
    bf16_t* QKV   = (bf16_t*)alloc((size_t)TOKENS * 1536 * 2);  // contiguous with Vt
    bf16_t* Vt    = (bf16_t*)alloc((size_t)32 * 64 * SEQ * 2);
    bf16_t* CTX   = (bf16_t*)alloc((size_t)TOKENS * 512 * 2);
    float*  ATTa  = (float*)alloc((size_t)TOKENS * 512 * 4);    // contiguous with ATTb
    float*  ATTb  = (float*)alloc((size_t)TOKENS * 512 * 4);
    float*  X1    = (float*)alloc((size_t)TOKENS * 512 * 4);
    bf16_t* X1b   = (bf16_t*)alloc((size_t)TOKENS * 512 * 2);

    bf16_t* H    = QKV;    // alias: QKV+Vt (33.55 MB exactly) dead after flash
    float*  FFNa = ATTa;   // alias: ATTa/ATTb dead after ln1 (contiguous pair)
    float*  FFNb = ATTb;

    cvt_weights<<<3074, 256, 0, stream>>>(Wq, Wk, Wv, Wo, W1, W2, bq, bk, bv,
                                          Wqkvb, Wob, W1b, W2b, bqkv, zbias);

    // fused QKV projection, fp32 A staged+converted in-kernel
    gemm_bt<128, 0, true, false><<<dim3(12, 64), 256, 0, stream>>>(
        src, Wqkvb, bqkv, zbias, QKV, TOKENS, 1536, 512);

    transpose_v<<<dim3(32, 32), 256, 0, stream>>>(QKV, Vt);
    flash_attn<<<dim3(32, 32), 128, 0, stream>>>(QKV, Vt, CTX);

    // Wo projection, split-K=2 -> ATTa/ATTb partials
    gemm_bt<64, 2, false, true><<<dim3(4, 128, 2), 256, 0, stream>>>(
        CTX, Wob, bo, zbias, ATTa, TOKENS, 512, 512);

    add_ln3<<<2048, 256, 0, stream>>>(src, ATTa, ATTb, g1, be1, X1, X1b);

    gemm_bt<128, 1, false, false><<<dim3(16, 64), 256, 0, stream>>>(
        X1b, W1b, b1, zbias, H, TOKENS, 2048, 512);

    // W2, split-K=2 -> FFNa/FFNb partials
    gemm_bt<64, 2, false, true><<<dim3(4, 128, 2), 256, 0, stream>>>(
        H, W2b, b2, zbias, FFNa, TOKENS, 512, 2048);

    add_ln3<<<2048, 256, 0, stream>>>(X1, FFNa, FFNb, g2, be2, out, nullptr);
}

// Round 6
// 357.169 us; speedup vs baseline: 1.2910x; 1.1174x over previous
//
#include <hip/hip_runtime.h>
#include <hip/hip_bf16.h>
#include <math.h>

// ---------------------------------------------------------------------------
typedef __bf16 bf16_t;
typedef __bf16 bf16x8 __attribute__((ext_vector_type(8)));
typedef __bf16 bf16x2 __attribute__((ext_vector_type(2)));
typedef float  f32x4  __attribute__((ext_vector_type(4)));

#define D_MODEL 512
#define NHEAD   8
#define HD      64
#define D_FF    2048
#define TOKENS  8192   // 4 * 2048
#define SEQ     2048
#define BATCH   4

// async global->LDS, 16B per lane; LDS dest = wave-uniform base + lane*16
__device__ __forceinline__ void gload16(const bf16_t* g, bf16_t* l)
{
    __builtin_amdgcn_global_load_lds(
        (const __attribute__((address_space(1))) void*)g,
        (__attribute__((address_space(3))) void*)l,
        16, 0, 0);
}

__device__ __forceinline__ void cvt4(const float* s, bf16_t* d)
{
    float4 v = *(const float4*)s;
    alignas(8) bf16_t t[4] = {(bf16_t)v.x, (bf16_t)v.y, (bf16_t)v.z, (bf16_t)v.w};
    *(uint2*)d = *(const uint2*)t;
}

// ---------------------------------------------------------------------------
// All weight conversions + bias concat + zero-bias fill in ONE kernel.
// ---------------------------------------------------------------------------
__global__ void cvt_weights(const float* __restrict__ Wq, const float* __restrict__ Wk,
                            const float* __restrict__ Wv, const float* __restrict__ Wo,
                            const float* __restrict__ W1, const float* __restrict__ W2,
                            const float* __restrict__ bq, const float* __restrict__ bk,
                            const float* __restrict__ bv,
                            bf16_t* __restrict__ Wqkvb, bf16_t* __restrict__ Wob,
                            bf16_t* __restrict__ W1b, bf16_t* __restrict__ W2b,
                            float* __restrict__ bqkv, float* __restrict__ zbias)
{
    int i = blockIdx.x * 256 + threadIdx.x;   // one thread = 4 elements
    if (i < 65536)        cvt4(Wq + (size_t)i * 4,            Wqkvb + (size_t)i * 4);
    else if (i < 131072)  cvt4(Wk + (size_t)(i - 65536) * 4,  Wqkvb + (size_t)i * 4);
    else if (i < 196608)  cvt4(Wv + (size_t)(i - 131072) * 4, Wqkvb + (size_t)i * 4);
    else if (i < 262144)  cvt4(Wo + (size_t)(i - 196608) * 4, Wob + (size_t)(i - 196608) * 4);
    else if (i < 524288)  cvt4(W1 + (size_t)(i - 262144) * 4, W1b + (size_t)(i - 262144) * 4);
    else if (i < 786432)  cvt4(W2 + (size_t)(i - 524288) * 4, W2b + (size_t)(i - 524288) * 4);
    else if (i < 786816) {
        int j = i - 786432;   // 0..383 -> 1536 bias floats
        const float* s = (j < 128) ? bq + j * 4 : (j < 256) ? bk + (j - 128) * 4
                                                            : bv + (j - 256) * 4;
        *(float4*)(bqkv + (j & 127) * 4 + (j >> 7) * 512) = *(const float4*)s;
    } else if (i < 786944) {
        int j = i - 786816;   // 0..127 -> 512 zero floats
        *(float4*)(zbias + j * 4) = make_float4(0.f, 0.f, 0.f, 0.f);
    }
}

// ---------------------------------------------------------------------------
// GEMM: C[M,N] = A[M,K] @ B[N,K]^T + bias, bf16 in, fp32 accum.
// BM x 128 tile, BK=32, 256 threads. global_load_lds staging for bf16 A/B;
// AF32: A is fp32 in global, converted during staging (fuses the src cvt).
// SPLIT2: gridDim.z==2, each z-half does K/2 and writes Cout + z*M*N;
//         z==1 uses biasz (zeros) so bias is applied exactly once.
// EPI: 0 = bias->bf16 ; 1 = bias+GELU->bf16 ; 2 = bias->fp32
// ---------------------------------------------------------------------------
template <int BM, int EPI, bool AF32, bool SPLIT2>
__global__ __launch_bounds__(256)
void gemm_bt(const void* __restrict__ Ain, const bf16_t* __restrict__ B,
             const float* __restrict__ bias, const float* __restrict__ biasz,
             void* __restrict__ Cout, int M, int N, int K)
{
    constexpr int MI = BM / 32;
    __shared__ bf16_t sA[BM][32];
    __shared__ bf16_t sB[128][32];
    bf16_t* sAf = &sA[0][0];
    bf16_t* sBf = &sB[0][0];

    const int tid  = threadIdx.x;
    const int wave = tid >> 6;
    const int lane = tid & 63;
    const int g    = lane >> 4;
    const int c16  = lane & 15;
    const int wm   = (wave >> 1) * (BM / 2);
    const int wn   = (wave & 1) * 64;
    const int m0   = blockIdx.y * BM;
    const int n0   = blockIdx.x * 128;

    const int zz    = SPLIT2 ? blockIdx.z : 0;
    const int Keff  = SPLIT2 ? (K >> 1) : K;
    const int kbase = zz * Keff;
    const float* bptr = (SPLIT2 && zz) ? biasz : bias;

    const f32x4 fz = {0.f, 0.f, 0.f, 0.f};
    f32x4 acc[MI][4];
#pragma unroll
    for (int i = 0; i < MI; i++)
#pragma unroll
        for (int j = 0; j < 4; j++) acc[i][j] = fz;

    const int srow = tid >> 2;
    const int scol = (tid & 3) * 8;
    const bf16_t* pa  = AF32 ? nullptr : (const bf16_t*)Ain + (size_t)(m0 + srow) * K + kbase + scol;
    const float*  paf = AF32 ? (const float*)Ain + (size_t)(m0 + srow) * K + kbase + scol : nullptr;
    const bf16_t* pb  = B + (size_t)(n0 + srow) * K + kbase + scol;

    for (int k0 = 0; k0 < Keff; k0 += 32) {
        float4 ua[BM / 64][2];
        if (AF32) {
#pragma unroll
            for (int i = 0; i < BM / 64; i++) {
                ua[i][0] = *(const float4*)(paf + (size_t)i * 64 * K + k0);
                ua[i][1] = *(const float4*)(paf + (size_t)i * 64 * K + k0 + 4);
            }
        }
        __syncthreads();                   // readers of previous tile done
        if (AF32) {
#pragma unroll
            for (int i = 0; i < BM / 64; i++) {
                alignas(16) bf16_t t[8];
#pragma unroll
                for (int j = 0; j < 4; j++) {
                    t[j]     = (bf16_t)((const float*)&ua[i][0])[j];
                    t[j + 4] = (bf16_t)((const float*)&ua[i][1])[j];
                }
                *(int4*)(sAf + i * 2048 + tid * 8) = *(const int4*)t;
            }
        } else {
#pragma unroll
            for (int i = 0; i < BM / 64; i++)
                gload16(pa + (size_t)i * 64 * K + k0, sAf + i * 2048 + tid * 8);
        }
#pragma unroll
        for (int i = 0; i < 2; i++)
            gload16(pb + (size_t)i * 64 * K + k0, sBf + i * 2048 + tid * 8);
        __syncthreads();

        bf16x8 af[MI], bfr[4];
#pragma unroll
        for (int i = 0; i < MI; i++)
            af[i] = *(const bf16x8*)&sA[wm + i * 16 + c16][g * 8];
#pragma unroll
        for (int j = 0; j < 4; j++)
            bfr[j] = *(const bf16x8*)&sB[wn + j * 16 + c16][g * 8];
#pragma unroll
        for (int mi = 0; mi < MI; mi++)
#pragma unroll
            for (int ni = 0; ni < 4; ni++)
                acc[mi][ni] = __builtin_amdgcn_mfma_f32_16x16x32_bf16(
                    af[mi], bfr[ni], acc[mi][ni], 0, 0, 0);
    }

    float* outf = (float*)Cout + (size_t)zz * M * N;
#pragma unroll
    for (int mi = 0; mi < MI; mi++) {
#pragma unroll
        for (int ni = 0; ni < 4; ni++) {
            const int col = n0 + wn + ni * 16 + c16;
            const float bv = bptr[col];
#pragma unroll
            for (int r = 0; r < 4; r++) {
                const int row = m0 + wm + mi * 16 + g * 4 + r;
                float v = acc[mi][ni][r] + bv;
                if (EPI == 1) v = 0.5f * v * (1.f + erff(v * 0.70710678118654752f));
                if (EPI == 2)
                    outf[(size_t)row * N + col] = v;
                else
                    ((bf16_t*)Cout)[(size_t)row * N + col] = (bf16_t)v;
            }
        }
    }
}

// ---------------------------------------------------------------------------
// transpose V out of QKV into Vt[bh][64][2048], t-dim interleaved within each
// 32-chunk: pos = 2*(t%16) + (t/16)%2 (+32*(t/32)). MFMA k-sums are
// permutation-invariant per 32-half, so flash uses this order for V^T and P.
// ---------------------------------------------------------------------------
__global__ __launch_bounds__(256)
void transpose_v(const bf16_t* __restrict__ qkv, bf16_t* __restrict__ vt)
{
    __shared__ bf16_t st[64][72];
    const int t0 = blockIdx.x * 64;
    const int bh = blockIdx.y;
    const int b = bh >> 3, h = bh & 7;
    const int tid = threadIdx.x;

    for (int c = tid; c < 512; c += 256) {
        int r = c >> 3, cj = (c & 7) * 8;
        const bf16_t* src = qkv + ((size_t)(b * SEQ + t0 + r)) * 1536 + 1024 + h * 64 + cj;
        *(int4*)&st[r][cj] = *(const int4*)src;
    }
    __syncthreads();
    for (int c = tid; c < 512; c += 256) {
        int d = c >> 3, pj = (c & 7) * 8;
        alignas(16) bf16_t tmp[8];
#pragma unroll
        for (int j = 0; j < 8; j++) {
            int p = pj + j;
            int t = (p & 32) + ((p & 1) << 4) + ((p & 31) >> 1);   // inverse perm
            tmp[j] = st[t][d];
        }
        *(int4*)(vt + ((size_t)(bh * 64 + d)) * SEQ + t0 + pj) = *(const int4*)tmp;
    }
}

// ---------------------------------------------------------------------------
// Flash attention v6 = v4/v5 structure, spill ACTUALLY fixed.
// grid (SEQ/64, B*H) = (32,32), block 128 (2 waves x 32 q-rows).
// Single-buffered K/V (30 KB LDS -> ~4-5 blocks/CU). Next K/V tile prefetched
// to registers, written to LDS after the read-barrier.
// amdgpu_waves_per_eu(2,2): pins the register allocator's occupancy TARGET
// (max, not just min) to 2 waves/EU -> 256-VGPR budget. R5's
// __launch_bounds__(128,2) only set the min; LLVM still chased 6 waves/EU
// (76 VGPRs) and spilled the prefetch to scratch (WRITE_SIZE 292 MB).
// LDS caps occupancy at ~2.5 waves/EU anyway, so nothing is lost.
// ---------------------------------------------------------------------------
__global__ __launch_bounds__(128)
__attribute__((amdgpu_waves_per_eu(2, 2)))
void flash_attn(const bf16_t* __restrict__ qkv, const bf16_t* __restrict__ vt,
                bf16_t* __restrict__ ctx)
{
    __shared__ bf16_t sK[64][72];    // 9 KB
    __shared__ bf16_t sVt[80][72];   // 11.25 KB ; rows 64..79: ones row + zeros
    __shared__ bf16_t sP[64][72];    // 9 KB

    const int bh = blockIdx.y;
    const int b = bh >> 3, h = bh & 7;
    const int q0 = blockIdx.x * 64;
    const int tid = threadIdx.x;
    const int wave = tid >> 6, lane = tid & 63;
    const int g = lane >> 4, c16 = lane & 15;

    // ones rows (never touched by staging)
    for (int c = tid; c < 16 * 72; c += 128)
        sVt[64 + c / 72][c % 72] = (c / 72 == 0) ? (bf16_t)1.0f : (bf16_t)0.0f;

    const float qscale = 0.125f * 1.4426950408889634f;   // 1/sqrt(64) * log2(e)
    bf16x8 aq[2][2];
#pragma unroll
    for (int mf = 0; mf < 2; mf++)
#pragma unroll
        for (int ks = 0; ks < 2; ks++) {
            bf16x8 v = *(const bf16x8*)(qkv +
                ((size_t)(b * SEQ + q0 + wave * 32 + mf * 16 + c16)) * 1536 +
                h * 64 + ks * 32 + g * 8);
#pragma unroll
            for (int j = 0; j < 8; j++) v[j] = (bf16_t)((float)v[j] * qscale);
            aq[mf][ks] = v;
        }

    const f32x4 fz = {0.f, 0.f, 0.f, 0.f};
    f32x4 acc_o[2][5];
#pragma unroll
    for (int mf = 0; mf < 2; mf++)
#pragma unroll
        for (int nd = 0; nd < 5; nd++) acc_o[mf][nd] = fz;

    // staging map: 4 rounds; round j -> row j*16 + (tid>>3), col chunk (tid&7)*8
    const int srow = tid >> 3;
    const int scol = (tid & 7) * 8;
    const bf16_t* pk = qkv + ((size_t)(b * SEQ) + srow) * 1536 + 512 + h * 64 + scol;
    const bf16_t* pv = vt + ((size_t)(bh * 64) + srow) * SEQ + scol;

    int4 rK[4], rV[4];
#pragma unroll
    for (int j = 0; j < 4; j++) {           // preload tile 0
        rK[j] = *(const int4*)(pk + (size_t)(j * 16) * 1536);
        rV[j] = *(const int4*)(pv + (size_t)(j * 16) * SEQ);
    }

    for (int it = 0; it < 32; ++it) {
        __syncthreads();   // both waves done reading previous tile
#pragma unroll
        for (int j = 0; j < 4; j++) {
            *(int4*)&sK[j * 16 + srow][scol]  = rK[j];
            *(int4*)&sVt[j * 16 + srow][scol] = rV[j];
        }
        const size_t kvn = (it < 31) ? (size_t)(it + 1) * 64 : (size_t)31 * 64;
#pragma unroll
        for (int j = 0; j < 4; j++) {       // prefetch next tile (overlaps compute)
            rK[j] = *(const int4*)(pk + (kvn + j * 16) * 1536);
            rV[j] = *(const int4*)(pv + kvn + (size_t)(j * 16) * SEQ);
        }
        __syncthreads();   // staged tile visible

        // S = (Q*qscale) K^T
        f32x4 accs[2][4];
#pragma unroll
        for (int mf = 0; mf < 2; mf++)
#pragma unroll
            for (int n = 0; n < 4; n++) accs[mf][n] = fz;
#pragma unroll
        for (int ks = 0; ks < 2; ks++)
#pragma unroll
            for (int n = 0; n < 4; n++) {
                bf16x8 bk = *(const bf16x8*)&sK[n * 16 + c16][ks * 32 + g * 8];
                accs[0][n] = __builtin_amdgcn_mfma_f32_16x16x32_bf16(aq[0][ks], bk, accs[0][n], 0, 0, 0);
                accs[1][n] = __builtin_amdgcn_mfma_f32_16x16x32_bf16(aq[1][ks], bk, accs[1][n], 0, 0, 0);
            }

        // P = 2^S, packed-pair stores in interleaved-t order (conflict-free)
#pragma unroll
        for (int mf = 0; mf < 2; mf++)
#pragma unroll
            for (int r = 0; r < 4; r++) {
                const int prow = wave * 32 + mf * 16 + g * 4 + r;
#pragma unroll
                for (int ks = 0; ks < 2; ks++) {
                    bf16x2 pp;
                    pp[0] = (bf16_t)__builtin_amdgcn_exp2f(accs[mf][2 * ks][r]);
                    pp[1] = (bf16_t)__builtin_amdgcn_exp2f(accs[mf][2 * ks + 1][r]);
                    *(bf16x2*)&sP[prow][ks * 32 + 2 * c16] = pp;
                }
            }

        // O += P @ [V | 1]  (sP rows wave-private; DS ops in-order per wave)
#pragma unroll
        for (int ks = 0; ks < 2; ks++) {
            bf16x8 ap0 = *(const bf16x8*)&sP[wave * 32 + c16][ks * 32 + g * 8];
            bf16x8 ap1 = *(const bf16x8*)&sP[wave * 32 + 16 + c16][ks * 32 + g * 8];
#pragma unroll
            for (int nd = 0; nd < 5; nd++) {
                bf16x8 vb = *(const bf16x8*)&sVt[nd * 16 + c16][ks * 32 + g * 8];
                acc_o[0][nd] = __builtin_amdgcn_mfma_f32_16x16x32_bf16(ap0, vb, acc_o[0][nd], 0, 0, 0);
                acc_o[1][nd] = __builtin_amdgcn_mfma_f32_16x16x32_bf16(ap1, vb, acc_o[1][nd], 0, 0, 0);
            }
        }
    }

    // epilogue: divide by l (ones-column sum sits at c16==0 lane of each group)
#pragma unroll
    for (int mf = 0; mf < 2; mf++)
#pragma unroll
        for (int r = 0; r < 4; r++) {
            float lv  = __shfl(acc_o[mf][4][r], lane & 48, 64);
            float inv = 1.0f / lv;
            const size_t base =
                ((size_t)(b * SEQ + q0 + wave * 32 + mf * 16 + g * 4 + r)) * 512 + h * 64;
#pragma unroll
            for (int nd = 0; nd < 4; nd++)
                ctx[base + nd * 16 + c16] = (bf16_t)(acc_o[mf][nd][r] * inv);
        }
}

// ---------------------------------------------------------------------------
// out = LayerNorm(a + b + c) * gamma + beta ; optional bf16 copy
// ---------------------------------------------------------------------------
__global__ __launch_bounds__(256)
void add_ln3(const float* __restrict__ a, const float* __restrict__ b,
             const float* __restrict__ c,
             const float* __restrict__ gamma, const float* __restrict__ beta,
             float* __restrict__ outf, bf16_t* __restrict__ outb)
{
    const int row  = blockIdx.x * 4 + (threadIdx.x >> 6);
    const int lane = threadIdx.x & 63;
    const size_t base = (size_t)row * 512 + lane * 8;

    float v[8];
#pragma unroll
    for (int h = 0; h < 2; h++) {
        float4 av = *(const float4*)(a + base + h * 4);
        float4 bv = *(const float4*)(b + base + h * 4);
        float4 cv = *(const float4*)(c + base + h * 4);
        v[h * 4 + 0] = av.x + bv.x + cv.x;
        v[h * 4 + 1] = av.y + bv.y + cv.y;
        v[h * 4 + 2] = av.z + bv.z + cv.z;
        v[h * 4 + 3] = av.w + bv.w + cv.w;
    }

    float s = 0.f;
#pragma unroll
    for (int i = 0; i < 8; i++) s += v[i];
#pragma unroll
    for (int off = 32; off > 0; off >>= 1) s += __shfl_xor(s, off);
    const float mu = s * (1.f / 512.f);

    float q = 0.f;
#pragma unroll
    for (int i = 0; i < 8; i++) { float d = v[i] - mu; q += d * d; }
#pragma unroll
    for (int off = 32; off > 0; off >>= 1) q += __shfl_xor(q, off);
    const float rstd = rsqrtf(q * (1.f / 512.f) + 1e-5f);

    float4 g0 = *(const float4*)(gamma + lane * 8);
    float4 g1 = *(const float4*)(gamma + lane * 8 + 4);
    float4 e0 = *(const float4*)(beta + lane * 8);
    float4 e1 = *(const float4*)(beta + lane * 8 + 4);
    const float gg[8] = {g0.x, g0.y, g0.z, g0.w, g1.x, g1.y, g1.z, g1.w};
    const float ee[8] = {e0.x, e0.y, e0.z, e0.w, e1.x, e1.y, e1.z, e1.w};

    float o[8];
#pragma unroll
    for (int i = 0; i < 8; i++) o[i] = (v[i] - mu) * rstd * gg[i] + ee[i];

    *(float4*)(outf + base)     = make_float4(o[0], o[1], o[2], o[3]);
    *(float4*)(outf + base + 4) = make_float4(o[4], o[5], o[6], o[7]);
    if (outb) {
        alignas(16) bf16_t ob[8];
#pragma unroll
        for (int i = 0; i < 8; i++) ob[i] = (bf16_t)o[i];
        *(int4*)(outb + base) = *(const int4*)ob;
    }
}

// ---------------------------------------------------------------------------
extern "C" void kernel_launch(void* const* d_in, const int* in_sizes, int n_in,
                              void* d_out, int out_size, void* d_ws, size_t ws_size,
                              hipStream_t stream)
{
    const float* src = (const float*)d_in[0];
    const float* Wq  = (const float*)d_in[1];  const float* bq  = (const float*)d_in[2];
    const float* Wk  = (const float*)d_in[3];  const float* bk  = (const float*)d_in[4];
    const float* Wv  = (const float*)d_in[5];  const float* bv  = (const float*)d_in[6];
    const float* Wo  = (const float*)d_in[7];  const float* bo  = (const float*)d_in[8];
    const float* W1  = (const float*)d_in[9];  const float* b1  = (const float*)d_in[10];
    const float* W2  = (const float*)d_in[11]; const float* b2  = (const float*)d_in[12];
    const float* g1  = (const float*)d_in[13]; const float* be1 = (const float*)d_in[14];
    const float* g2  = (const float*)d_in[15]; const float* be2 = (const float*)d_in[16];
    float* out = (float*)d_out;

    char* ws = (char*)d_ws;
    size_t off = 0;
    auto alloc = [&](size_t bytes) -> void* {
        void* p = ws + off;
        off = (off + bytes + 255) & ~(size_t)255;
        return p;
    };

    bf16_t* Wqkvb = (bf16_t*)alloc((size_t)1536 * 512 * 2);
    bf16_t* Wob   = (bf16_t*)alloc((size_t)512 * 512 * 2);
    bf16_t* W1b   = (bf16_t*)alloc((size_t)2048 * 512 * 2);
    bf16_t* W2b   = (bf16_t*)alloc((size_t)512 * 2048 * 2);
    float*  bqkv  = (float*)alloc(1536 * 4);
    float*  zbias = (float*)alloc(512 * 4);
    bf16_t* QKV   = (bf16_t*)alloc((size_t)TOKENS * 1536 * 2);  // contiguous with Vt
    bf16_t* Vt    = (bf16_t*)alloc((size_t)32 * 64 * SEQ * 2);
    bf16_t* CTX   = (bf16_t*)alloc((size_t)TOKENS * 512 * 2);
    float*  ATTa  = (float*)alloc((size_t)TOKENS * 512 * 4);    // contiguous with ATTb
    float*  ATTb  = (float*)alloc((size_t)TOKENS * 512 * 4);
    float*  X1    = (float*)alloc((size_t)TOKENS * 512 * 4);
    bf16_t* X1b   = (bf16_t*)alloc((size_t)TOKENS * 512 * 2);

    bf16_t* H    = QKV;    // alias: QKV+Vt (33.55 MB exactly) dead after flash
    float*  FFNa = ATTa;   // alias: ATTa/ATTb dead after ln1 (contiguous pair)
    float*  FFNb = ATTb;

    cvt_weights<<<3074, 256, 0, stream>>>(Wq, Wk, Wv, Wo, W1, W2, bq, bk, bv,
                                          Wqkvb, Wob, W1b, W2b, bqkv, zbias);

    // fused QKV projection, fp32 A staged+converted in-kernel
    gemm_bt<128, 0, true, false><<<dim3(12, 64), 256, 0, stream>>>(
        src, Wqkvb, bqkv, zbias, QKV, TOKENS, 1536, 512);

    transpose_v<<<dim3(32, 32), 256, 0, stream>>>(QKV, Vt);
    flash_attn<<<dim3(32, 32), 128, 0, stream>>>(QKV, Vt, CTX);

    // Wo projection, split-K=2 -> ATTa/ATTb partials
    gemm_bt<64, 2, false, true><<<dim3(4, 128, 2), 256, 0, stream>>>(
        CTX, Wob, bo, zbias, ATTa, TOKENS, 512, 512);

    add_ln3<<<2048, 256, 0, stream>>>(src, ATTa, ATTb, g1, be1, X1, X1b);

    gemm_bt<128, 1, false, false><<<dim3(16, 64), 256, 0, stream>>>(
        X1b, W1b, b1, zbias, H, TOKENS, 2048, 512);

    // W2, split-K=2 -> FFNa/FFNb partials
    gemm_bt<64, 2, false, true><<<dim3(4, 128, 2), 256, 0, stream>>>(
        H, W2b, b2, zbias, FFNa, TOKENS, 512, 2048);

    add_ln3<<<2048, 256, 0, stream>>>(X1, FFNa, FFNb, g2, be2, out, nullptr);
}

// Round 7
// 309.226 us; speedup vs baseline: 1.4912x; 1.1550x over previous
//
#include <hip/hip_runtime.h>
#include <hip/hip_bf16.h>
#include <math.h>

// ---------------------------------------------------------------------------
typedef __bf16 bf16_t;
typedef __bf16 bf16x8 __attribute__((ext_vector_type(8)));
typedef __bf16 bf16x2 __attribute__((ext_vector_type(2)));
typedef float  f32x4  __attribute__((ext_vector_type(4)));

#define D_MODEL 512
#define NHEAD   8
#define HD      64
#define D_FF    2048
#define TOKENS  8192   // 4 * 2048
#define SEQ     2048
#define BATCH   4

// async global->LDS, 16B per lane; LDS dest = wave-uniform base + lane*16
__device__ __forceinline__ void gload16(const bf16_t* g, bf16_t* l)
{
    __builtin_amdgcn_global_load_lds(
        (const __attribute__((address_space(1))) void*)g,
        (__attribute__((address_space(3))) void*)l,
        16, 0, 0);
}

__device__ __forceinline__ void cvt4(const float* s, bf16_t* d)
{
    float4 v = *(const float4*)s;
    alignas(8) bf16_t t[4] = {(bf16_t)v.x, (bf16_t)v.y, (bf16_t)v.z, (bf16_t)v.w};
    *(uint2*)d = *(const uint2*)t;
}

// ---------------------------------------------------------------------------
// All weight conversions + bias concat + zero-bias fill in ONE kernel.
// ---------------------------------------------------------------------------
__global__ void cvt_weights(const float* __restrict__ Wq, const float* __restrict__ Wk,
                            const float* __restrict__ Wv, const float* __restrict__ Wo,
                            const float* __restrict__ W1, const float* __restrict__ W2,
                            const float* __restrict__ bq, const float* __restrict__ bk,
                            const float* __restrict__ bv,
                            bf16_t* __restrict__ Wqkvb, bf16_t* __restrict__ Wob,
                            bf16_t* __restrict__ W1b, bf16_t* __restrict__ W2b,
                            float* __restrict__ bqkv, float* __restrict__ zbias)
{
    int i = blockIdx.x * 256 + threadIdx.x;   // one thread = 4 elements
    if (i < 65536)        cvt4(Wq + (size_t)i * 4,            Wqkvb + (size_t)i * 4);
    else if (i < 131072)  cvt4(Wk + (size_t)(i - 65536) * 4,  Wqkvb + (size_t)i * 4);
    else if (i < 196608)  cvt4(Wv + (size_t)(i - 131072) * 4, Wqkvb + (size_t)i * 4);
    else if (i < 262144)  cvt4(Wo + (size_t)(i - 196608) * 4, Wob + (size_t)(i - 196608) * 4);
    else if (i < 524288)  cvt4(W1 + (size_t)(i - 262144) * 4, W1b + (size_t)(i - 262144) * 4);
    else if (i < 786432)  cvt4(W2 + (size_t)(i - 524288) * 4, W2b + (size_t)(i - 524288) * 4);
    else if (i < 786816) {
        int j = i - 786432;   // 0..383 -> 1536 bias floats
        const float* s = (j < 128) ? bq + j * 4 : (j < 256) ? bk + (j - 128) * 4
                                                            : bv + (j - 256) * 4;
        *(float4*)(bqkv + (j & 127) * 4 + (j >> 7) * 512) = *(const float4*)s;
    } else if (i < 786944) {
        int j = i - 786816;   // 0..127 -> 512 zero floats
        *(float4*)(zbias + j * 4) = make_float4(0.f, 0.f, 0.f, 0.f);
    }
}

// ---------------------------------------------------------------------------
// GEMM: C[M,N] = A[M,K] @ B[N,K]^T + bias, bf16 in, fp32 accum.
// BM x 128 tile, BK=32, 256 threads. global_load_lds staging for bf16 A/B;
// AF32: A is fp32 in global, converted during staging (fuses the src cvt).
// SPLIT2: gridDim.z==2, each z-half does K/2 and writes Cout + z*M*N;
//         z==1 uses biasz (zeros) so bias is applied exactly once.
// EPI: 0 = bias->bf16 ; 1 = bias+GELU->bf16 ; 2 = bias->fp32
// ---------------------------------------------------------------------------
template <int BM, int EPI, bool AF32, bool SPLIT2>
__global__ __launch_bounds__(256)
void gemm_bt(const void* __restrict__ Ain, const bf16_t* __restrict__ B,
             const float* __restrict__ bias, const float* __restrict__ biasz,
             void* __restrict__ Cout, int M, int N, int K)
{
    constexpr int MI = BM / 32;
    __shared__ bf16_t sA[BM][32];
    __shared__ bf16_t sB[128][32];
    bf16_t* sAf = &sA[0][0];
    bf16_t* sBf = &sB[0][0];

    const int tid  = threadIdx.x;
    const int wave = tid >> 6;
    const int lane = tid & 63;
    const int g    = lane >> 4;
    const int c16  = lane & 15;
    const int wm   = (wave >> 1) * (BM / 2);
    const int wn   = (wave & 1) * 64;
    const int m0   = blockIdx.y * BM;
    const int n0   = blockIdx.x * 128;

    const int zz    = SPLIT2 ? blockIdx.z : 0;
    const int Keff  = SPLIT2 ? (K >> 1) : K;
    const int kbase = zz * Keff;
    const float* bptr = (SPLIT2 && zz) ? biasz : bias;

    const f32x4 fz = {0.f, 0.f, 0.f, 0.f};
    f32x4 acc[MI][4];
#pragma unroll
    for (int i = 0; i < MI; i++)
#pragma unroll
        for (int j = 0; j < 4; j++) acc[i][j] = fz;

    const int srow = tid >> 2;
    const int scol = (tid & 3) * 8;
    const bf16_t* pa  = AF32 ? nullptr : (const bf16_t*)Ain + (size_t)(m0 + srow) * K + kbase + scol;
    const float*  paf = AF32 ? (const float*)Ain + (size_t)(m0 + srow) * K + kbase + scol : nullptr;
    const bf16_t* pb  = B + (size_t)(n0 + srow) * K + kbase + scol;

    for (int k0 = 0; k0 < Keff; k0 += 32) {
        float4 ua[BM / 64][2];
        if (AF32) {
#pragma unroll
            for (int i = 0; i < BM / 64; i++) {
                ua[i][0] = *(const float4*)(paf + (size_t)i * 64 * K + k0);
                ua[i][1] = *(const float4*)(paf + (size_t)i * 64 * K + k0 + 4);
            }
        }
        __syncthreads();                   // readers of previous tile done
        if (AF32) {
#pragma unroll
            for (int i = 0; i < BM / 64; i++) {
                alignas(16) bf16_t t[8];
#pragma unroll
                for (int j = 0; j < 4; j++) {
                    t[j]     = (bf16_t)((const float*)&ua[i][0])[j];
                    t[j + 4] = (bf16_t)((const float*)&ua[i][1])[j];
                }
                *(int4*)(sAf + i * 2048 + tid * 8) = *(const int4*)t;
            }
        } else {
#pragma unroll
            for (int i = 0; i < BM / 64; i++)
                gload16(pa + (size_t)i * 64 * K + k0, sAf + i * 2048 + tid * 8);
        }
#pragma unroll
        for (int i = 0; i < 2; i++)
            gload16(pb + (size_t)i * 64 * K + k0, sBf + i * 2048 + tid * 8);
        __syncthreads();

        bf16x8 af[MI], bfr[4];
#pragma unroll
        for (int i = 0; i < MI; i++)
            af[i] = *(const bf16x8*)&sA[wm + i * 16 + c16][g * 8];
#pragma unroll
        for (int j = 0; j < 4; j++)
            bfr[j] = *(const bf16x8*)&sB[wn + j * 16 + c16][g * 8];
#pragma unroll
        for (int mi = 0; mi < MI; mi++)
#pragma unroll
            for (int ni = 0; ni < 4; ni++)
                acc[mi][ni] = __builtin_amdgcn_mfma_f32_16x16x32_bf16(
                    af[mi], bfr[ni], acc[mi][ni], 0, 0, 0);
    }

    float* outf = (float*)Cout + (size_t)zz * M * N;
#pragma unroll
    for (int mi = 0; mi < MI; mi++) {
#pragma unroll
        for (int ni = 0; ni < 4; ni++) {
            const int col = n0 + wn + ni * 16 + c16;
            const float bv = bptr[col];
#pragma unroll
            for (int r = 0; r < 4; r++) {
                const int row = m0 + wm + mi * 16 + g * 4 + r;
                float v = acc[mi][ni][r] + bv;
                if (EPI == 1) v = 0.5f * v * (1.f + erff(v * 0.70710678118654752f));
                if (EPI == 2)
                    outf[(size_t)row * N + col] = v;
                else
                    ((bf16_t*)Cout)[(size_t)row * N + col] = (bf16_t)v;
            }
        }
    }
}

// ---------------------------------------------------------------------------
// transpose V out of QKV into Vt[bh][64][2048], t-dim interleaved within each
// 32-chunk: pos = 2*(t%16) + (t/16)%2 (+32*(t/32)). MFMA k-sums are
// permutation-invariant per 32-half, so flash uses this order for V^T and P.
// ---------------------------------------------------------------------------
__global__ __launch_bounds__(256)
void transpose_v(const bf16_t* __restrict__ qkv, bf16_t* __restrict__ vt)
{
    __shared__ bf16_t st[64][72];
    const int t0 = blockIdx.x * 64;
    const int bh = blockIdx.y;
    const int b = bh >> 3, h = bh & 7;
    const int tid = threadIdx.x;

    for (int c = tid; c < 512; c += 256) {
        int r = c >> 3, cj = (c & 7) * 8;
        const bf16_t* src = qkv + ((size_t)(b * SEQ + t0 + r)) * 1536 + 1024 + h * 64 + cj;
        *(int4*)&st[r][cj] = *(const int4*)src;
    }
    __syncthreads();
    for (int c = tid; c < 512; c += 256) {
        int d = c >> 3, pj = (c & 7) * 8;
        alignas(16) bf16_t tmp[8];
#pragma unroll
        for (int j = 0; j < 8; j++) {
            int p = pj + j;
            int t = (p & 32) + ((p & 1) << 4) + ((p & 31) >> 1);   // inverse perm
            tmp[j] = st[t][d];
        }
        *(int4*)(vt + ((size_t)(bh * 64 + d)) * SEQ + t0 + pj) = *(const int4*)tmp;
    }
}

// ---------------------------------------------------------------------------
// Flash attention v7: DMA staging, zero staging VGPRs.
// grid (SEQ/128, B*H) = (16,32), block 256 (4 waves x 32 q-rows).
// K/V double-buffered in UNPADDED [64][64] LDS, staged by global_load_lds
// with XOR-swizzled 16B-chunk placement: phys_chunk = logical ^ (row&7).
// Fragment reads then start at bank (phys_chunk*4)%32 with 8 lanes per chunk
// value -> each of the 8 b128 phases covers all 32 banks (conflict-free).
// ONE barrier per iter: DMA for tile i+1 issued right after the barrier that
// publishes tile i, so the compiler's vmcnt(0)-before-barrier drains loads
// that have had a full compute phase in flight.
// Q pre-scaled by (1/8)*log2(e) -> P = exp2(S). Row-sum l via sOnes block.
// ---------------------------------------------------------------------------
__global__ __launch_bounds__(256)
void flash_attn(const bf16_t* __restrict__ qkv, const bf16_t* __restrict__ vt,
                bf16_t* __restrict__ ctx)
{
    __shared__ bf16_t sK[2][64][64];    // 16 KB
    __shared__ bf16_t sVt[2][64][64];   // 16 KB
    __shared__ bf16_t sOnes[16][72];    // 2.25 KB ; row 0 = ones, rest zero
    __shared__ bf16_t sP[128][72];      // 18 KB

    const int bh = blockIdx.y;
    const int b = bh >> 3, h = bh & 7;
    const int q0 = blockIdx.x * 128;
    const int tid = threadIdx.x;
    const int wave = tid >> 6, lane = tid & 63;
    const int g = lane >> 4, c16 = lane & 15;

    // ones region (row 0 = logical V^T row 64)
    for (int c = tid; c < 16 * 72; c += 256)
        sOnes[c / 72][c % 72] = (c / 72 == 0) ? (bf16_t)1.0f : (bf16_t)0.0f;

    const float qscale = 0.125f * 1.4426950408889634f;   // 1/sqrt(64) * log2(e)
    bf16x8 aq[2][2];
#pragma unroll
    for (int mf = 0; mf < 2; mf++)
#pragma unroll
        for (int ks = 0; ks < 2; ks++) {
            bf16x8 v = *(const bf16x8*)(qkv +
                ((size_t)(b * SEQ + q0 + wave * 32 + mf * 16 + c16)) * 1536 +
                h * 64 + ks * 32 + g * 8);
#pragma unroll
            for (int j = 0; j < 8; j++) v[j] = (bf16_t)((float)v[j] * qscale);
            aq[mf][ks] = v;
        }

    const f32x4 fz = {0.f, 0.f, 0.f, 0.f};
    f32x4 acc_o[2][5];
#pragma unroll
    for (int mf = 0; mf < 2; mf++)
#pragma unroll
        for (int nd = 0; nd < 5; nd++) acc_o[mf][nd] = fz;

    // DMA staging map: flat 16B-chunk index f = issue*256 + tid covers the
    // 8 KB tile; LDS slot f (linear) holds physical chunk (row=f>>3, p=f&7),
    // which receives LOGICAL chunk l = p ^ (row&7) from global.
    const int f0 = tid,        r0 = f0 >> 3, l0 = (f0 & 7) ^ (r0 & 7);
    const int f1 = tid + 256,  r1 = f1 >> 3, l1 = (f1 & 7) ^ (r1 & 7);
    const bf16_t* gK0 = qkv + ((size_t)(b * SEQ + r0)) * 1536 + 512 + h * 64 + l0 * 8;
    const bf16_t* gK1 = qkv + ((size_t)(b * SEQ + r1)) * 1536 + 512 + h * 64 + l1 * 8;
    const bf16_t* gV0 = vt + ((size_t)(bh * 64 + r0)) * SEQ + l0 * 8;
    const bf16_t* gV1 = vt + ((size_t)(bh * 64 + r1)) * SEQ + l1 * 8;
    bf16_t* lK = &sK[0][0][0];
    bf16_t* lV = &sVt[0][0][0];

    // tile 0 -> buf 0
    gload16(gK0, lK + f0 * 8);
    gload16(gK1, lK + f1 * 8);
    gload16(gV0, lV + f0 * 8);
    gload16(gV1, lV + f1 * 8);

    for (int it = 0; it < 32; ++it) {
        const int cur = it & 1;
        __syncthreads();   // drains DMA for tile it; joins all waves
        if (it < 31) {     // issue tile it+1 into the other buffer
            const size_t kv = (size_t)(it + 1) * 64;
            const int bo = (cur ^ 1) * 4096;
            gload16(gK0 + kv * 1536, lK + bo + f0 * 8);
            gload16(gK1 + kv * 1536, lK + bo + f1 * 8);
            gload16(gV0 + kv,        lV + bo + f0 * 8);
            gload16(gV1 + kv,        lV + bo + f1 * 8);
        }

        // S = (Q*qscale) K^T ; swizzled read: row&7 == c16&7
        f32x4 accs[2][4];
#pragma unroll
        for (int mf = 0; mf < 2; mf++)
#pragma unroll
            for (int n = 0; n < 4; n++) accs[mf][n] = fz;
#pragma unroll
        for (int ks = 0; ks < 2; ks++)
#pragma unroll
            for (int n = 0; n < 4; n++) {
                const int pc = ((ks * 4 + g) ^ (c16 & 7)) * 8;
                bf16x8 bk = *(const bf16x8*)&sK[cur][n * 16 + c16][pc];
                accs[0][n] = __builtin_amdgcn_mfma_f32_16x16x32_bf16(aq[0][ks], bk, accs[0][n], 0, 0, 0);
                accs[1][n] = __builtin_amdgcn_mfma_f32_16x16x32_bf16(aq[1][ks], bk, accs[1][n], 0, 0, 0);
            }

        // P = 2^S, packed-pair stores in interleaved-t order
#pragma unroll
        for (int mf = 0; mf < 2; mf++)
#pragma unroll
            for (int r = 0; r < 4; r++) {
                const int prow = wave * 32 + mf * 16 + g * 4 + r;
#pragma unroll
                for (int ks = 0; ks < 2; ks++) {
                    bf16x2 pp;
                    pp[0] = (bf16_t)__builtin_amdgcn_exp2f(accs[mf][2 * ks][r]);
                    pp[1] = (bf16_t)__builtin_amdgcn_exp2f(accs[mf][2 * ks + 1][r]);
                    *(bf16x2*)&sP[prow][ks * 32 + 2 * c16] = pp;
                }
            }

        // O += P @ [V | 1]  (sP rows wave-private; DS ops in-order per wave)
#pragma unroll
        for (int ks = 0; ks < 2; ks++) {
            bf16x8 ap0 = *(const bf16x8*)&sP[wave * 32 + c16][ks * 32 + g * 8];
            bf16x8 ap1 = *(const bf16x8*)&sP[wave * 32 + 16 + c16][ks * 32 + g * 8];
#pragma unroll
            for (int nd = 0; nd < 5; nd++) {
                bf16x8 vb;
                if (nd < 4) {
                    const int pc = ((ks * 4 + g) ^ (c16 & 7)) * 8;
                    vb = *(const bf16x8*)&sVt[cur][nd * 16 + c16][pc];
                } else {
                    vb = *(const bf16x8*)&sOnes[c16][ks * 32 + g * 8];
                }
                acc_o[0][nd] = __builtin_amdgcn_mfma_f32_16x16x32_bf16(ap0, vb, acc_o[0][nd], 0, 0, 0);
                acc_o[1][nd] = __builtin_amdgcn_mfma_f32_16x16x32_bf16(ap1, vb, acc_o[1][nd], 0, 0, 0);
            }
        }
    }

    // epilogue: divide by l (ones-column sum sits at c16==0 lane of each group)
#pragma unroll
    for (int mf = 0; mf < 2; mf++)
#pragma unroll
        for (int r = 0; r < 4; r++) {
            float lv  = __shfl(acc_o[mf][4][r], lane & 48, 64);
            float inv = 1.0f / lv;
            const size_t base =
                ((size_t)(b * SEQ + q0 + wave * 32 + mf * 16 + g * 4 + r)) * 512 + h * 64;
#pragma unroll
            for (int nd = 0; nd < 4; nd++)
                ctx[base + nd * 16 + c16] = (bf16_t)(acc_o[mf][nd][r] * inv);
        }
}

// ---------------------------------------------------------------------------
// out = LayerNorm(a + b + c) * gamma + beta ; optional bf16 copy
// ---------------------------------------------------------------------------
__global__ __launch_bounds__(256)
void add_ln3(const float* __restrict__ a, const float* __restrict__ b,
             const float* __restrict__ c,
             const float* __restrict__ gamma, const float* __restrict__ beta,
             float* __restrict__ outf, bf16_t* __restrict__ outb)
{
    const int row  = blockIdx.x * 4 + (threadIdx.x >> 6);
    const int lane = threadIdx.x & 63;
    const size_t base = (size_t)row * 512 + lane * 8;

    float v[8];
#pragma unroll
    for (int h = 0; h < 2; h++) {
        float4 av = *(const float4*)(a + base + h * 4);
        float4 bv = *(const float4*)(b + base + h * 4);
        float4 cv = *(const float4*)(c + base + h * 4);
        v[h * 4 + 0] = av.x + bv.x + cv.x;
        v[h * 4 + 1] = av.y + bv.y + cv.y;
        v[h * 4 + 2] = av.z + bv.z + cv.z;
        v[h * 4 + 3] = av.w + bv.w + cv.w;
    }

    float s = 0.f;
#pragma unroll
    for (int i = 0; i < 8; i++) s += v[i];
#pragma unroll
    for (int off = 32; off > 0; off >>= 1) s += __shfl_xor(s, off);
    const float mu = s * (1.f / 512.f);

    float q = 0.f;
#pragma unroll
    for (int i = 0; i < 8; i++) { float d = v[i] - mu; q += d * d; }
#pragma unroll
    for (int off = 32; off > 0; off >>= 1) q += __shfl_xor(q, off);
    const float rstd = rsqrtf(q * (1.f / 512.f) + 1e-5f);

    float4 g0 = *(const float4*)(gamma + lane * 8);
    float4 g1 = *(const float4*)(gamma + lane * 8 + 4);
    float4 e0 = *(const float4*)(beta + lane * 8);
    float4 e1 = *(const float4*)(beta + lane * 8 + 4);
    const float gg[8] = {g0.x, g0.y, g0.z, g0.w, g1.x, g1.y, g1.z, g1.w};
    const float ee[8] = {e0.x, e0.y, e0.z, e0.w, e1.x, e1.y, e1.z, e1.w};

    float o[8];
#pragma unroll
    for (int i = 0; i < 8; i++) o[i] = (v[i] - mu) * rstd * gg[i] + ee[i];

    *(float4*)(outf + base)     = make_float4(o[0], o[1], o[2], o[3]);
    *(float4*)(outf + base + 4) = make_float4(o[4], o[5], o[6], o[7]);
    if (outb) {
        alignas(16) bf16_t ob[8];
#pragma unroll
        for (int i = 0; i < 8; i++) ob[i] = (bf16_t)o[i];
        *(int4*)(outb + base) = *(const int4*)ob;
    }
}

// ---------------------------------------------------------------------------
extern "C" void kernel_launch(void* const* d_in, const int* in_sizes, int n_in,
                              void* d_out, int out_size, void* d_ws, size_t ws_size,
                              hipStream_t stream)
{
    const float* src = (const float*)d_in[0];
    const float* Wq  = (const float*)d_in[1];  const float* bq  = (const float*)d_in[2];
    const float* Wk  = (const float*)d_in[3];  const float* bk  = (const float*)d_in[4];
    const float* Wv  = (const float*)d_in[5];  const float* bv  = (const float*)d_in[6];
    const float* Wo  = (const float*)d_in[7];  const float* bo  = (const float*)d_in[8];
    const float* W1  = (const float*)d_in[9];  const float* b1  = (const float*)d_in[10];
    const float* W2  = (const float*)d_in[11]; const float* b2  = (const float*)d_in[12];
    const float* g1  = (const float*)d_in[13]; const float* be1 = (const float*)d_in[14];
    const float* g2  = (const float*)d_in[15]; const float* be2 = (const float*)d_in[16];
    float* out = (float*)d_out;

    char* ws = (char*)d_ws;
    size_t off = 0;
    auto alloc = [&](size_t bytes) -> void* {
        void* p = ws + off;
        off = (off + bytes + 255) & ~(size_t)255;
        return p;
    };

    bf16_t* Wqkvb = (bf16_t*)alloc((size_t)1536 * 512 * 2);
    bf16_t* Wob   = (bf16_t*)alloc((size_t)512 * 512 * 2);
    bf16_t* W1b   = (bf16_t*)alloc((size_t)2048 * 512 * 2);
    bf16_t* W2b   = (bf16_t*)alloc((size_t)512 * 2048 * 2);
    float*  bqkv  = (float*)alloc(1536 * 4);
    float*  zbias = (float*)alloc(512 * 4);
    bf16_t* QKV   = (bf16_t*)alloc((size_t)TOKENS * 1536 * 2);  // contiguous with Vt
    bf16_t* Vt    = (bf16_t*)alloc((size_t)32 * 64 * SEQ * 2);
    bf16_t* CTX   = (bf16_t*)alloc((size_t)TOKENS * 512 * 2);
    float*  ATTa  = (float*)alloc((size_t)TOKENS * 512 * 4);    // contiguous with ATTb
    float*  ATTb  = (float*)alloc((size_t)TOKENS * 512 * 4);
    float*  X1    = (float*)alloc((size_t)TOKENS * 512 * 4);
    bf16_t* X1b   = (bf16_t*)alloc((size_t)TOKENS * 512 * 2);

    bf16_t* H    = QKV;    // alias: QKV+Vt (33.55 MB exactly) dead after flash
    float*  FFNa = ATTa;   // alias: ATTa/ATTb dead after ln1 (contiguous pair)
    float*  FFNb = ATTb;

    cvt_weights<<<3074, 256, 0, stream>>>(Wq, Wk, Wv, Wo, W1, W2, bq, bk, bv,
                                          Wqkvb, Wob, W1b, W2b, bqkv, zbias);

    // fused QKV projection, fp32 A staged+converted in-kernel
    gemm_bt<128, 0, true, false><<<dim3(12, 64), 256, 0, stream>>>(
        src, Wqkvb, bqkv, zbias, QKV, TOKENS, 1536, 512);

    transpose_v<<<dim3(32, 32), 256, 0, stream>>>(QKV, Vt);
    flash_attn<<<dim3(16, 32), 256, 0, stream>>>(QKV, Vt, CTX);

    // Wo projection, split-K=2 -> ATTa/ATTb partials
    gemm_bt<64, 2, false, true><<<dim3(4, 128, 2), 256, 0, stream>>>(
        CTX, Wob, bo, zbias, ATTa, TOKENS, 512, 512);

    add_ln3<<<2048, 256, 0, stream>>>(src, ATTa, ATTb, g1, be1, X1, X1b);

    gemm_bt<128, 1, false, false><<<dim3(16, 64), 256, 0, stream>>>(
        X1b, W1b, b1, zbias, H, TOKENS, 2048, 512);

    // W2, split-K=2 -> FFNa/FFNb partials
    gemm_bt<64, 2, false, true><<<dim3(4, 128, 2), 256, 0, stream>>>(
        H, W2b, b2, zbias, FFNa, TOKENS, 512, 2048);

    add_ln3<<<2048, 256, 0, stream>>>(X1, FFNa, FFNb, g2, be2, out, nullptr);
}

// Round 8
// 296.488 us; speedup vs baseline: 1.5553x; 1.0430x over previous
//
#include <hip/hip_runtime.h>
#include <hip/hip_bf16.h>
#include <math.h>

// ---------------------------------------------------------------------------
typedef __bf16 bf16_t;
typedef __bf16 bf16x8 __attribute__((ext_vector_type(8)));
typedef __bf16 bf16x2 __attribute__((ext_vector_type(2)));
typedef float  f32x4  __attribute__((ext_vector_type(4)));

#define D_MODEL 512
#define NHEAD   8
#define HD      64
#define D_FF    2048
#define TOKENS  8192   // 4 * 2048
#define SEQ     2048
#define BATCH   4

// async global->LDS, 16B per lane; LDS dest = wave-uniform base + lane*16
__device__ __forceinline__ void gload16(const bf16_t* g, bf16_t* l)
{
    __builtin_amdgcn_global_load_lds(
        (const __attribute__((address_space(1))) void*)g,
        (__attribute__((address_space(3))) void*)l,
        16, 0, 0);
}

__device__ __forceinline__ void cvt4(const float* s, bf16_t* d)
{
    float4 v = *(const float4*)s;
    alignas(8) bf16_t t[4] = {(bf16_t)v.x, (bf16_t)v.y, (bf16_t)v.z, (bf16_t)v.w};
    *(uint2*)d = *(const uint2*)t;
}

// ---------------------------------------------------------------------------
// src + all weight conversions + bias concat + zero-bias fill in ONE kernel.
// ---------------------------------------------------------------------------
__global__ void cvt_weights(const float* __restrict__ src,
                            const float* __restrict__ Wq, const float* __restrict__ Wk,
                            const float* __restrict__ Wv, const float* __restrict__ Wo,
                            const float* __restrict__ W1, const float* __restrict__ W2,
                            const float* __restrict__ bq, const float* __restrict__ bk,
                            const float* __restrict__ bv,
                            bf16_t* __restrict__ Xb,
                            bf16_t* __restrict__ Wqkvb, bf16_t* __restrict__ Wob,
                            bf16_t* __restrict__ W1b, bf16_t* __restrict__ W2b,
                            float* __restrict__ bqkv, float* __restrict__ zbias)
{
    int i = blockIdx.x * 256 + threadIdx.x;   // one thread = 4 elements
    if (i < 1048576) { cvt4(src + (size_t)i * 4, Xb + (size_t)i * 4); return; }
    i -= 1048576;
    if (i < 65536)        cvt4(Wq + (size_t)i * 4,            Wqkvb + (size_t)i * 4);
    else if (i < 131072)  cvt4(Wk + (size_t)(i - 65536) * 4,  Wqkvb + (size_t)i * 4);
    else if (i < 196608)  cvt4(Wv + (size_t)(i - 131072) * 4, Wqkvb + (size_t)i * 4);
    else if (i < 262144)  cvt4(Wo + (size_t)(i - 196608) * 4, Wob + (size_t)(i - 196608) * 4);
    else if (i < 524288)  cvt4(W1 + (size_t)(i - 262144) * 4, W1b + (size_t)(i - 262144) * 4);
    else if (i < 786432)  cvt4(W2 + (size_t)(i - 524288) * 4, W2b + (size_t)(i - 524288) * 4);
    else if (i < 786816) {
        int j = i - 786432;   // 0..383 -> 1536 bias floats
        const float* s = (j < 128) ? bq + j * 4 : (j < 256) ? bk + (j - 128) * 4
                                                            : bv + (j - 256) * 4;
        *(float4*)(bqkv + (j & 127) * 4 + (j >> 7) * 512) = *(const float4*)s;
    } else if (i < 786944) {
        int j = i - 786816;   // 0..127 -> 512 zero floats
        *(float4*)(zbias + j * 4) = make_float4(0.f, 0.f, 0.f, 0.f);
    }
}

// ---------------------------------------------------------------------------
// GEMM v2: C[M,N] = A[M,K] @ B[N,K]^T + bias, bf16 in, fp32 accum.
// BM x 128 tile, BK=32, 256 threads. DOUBLE-BUFFERED global_load_lds with a
// SINGLE barrier per iter: DMA for tile k+1 is issued right after the barrier
// that publishes tile k, so every load has a full compute phase in flight
// before the next barrier's vmcnt(0) drain (flash-v7 pattern). The old
// 2-barrier m97 loop stalled serially every iter -> 200 TF at K=512.
// SPLIT2: gridDim.z==2, each z-half does K/2, writes Cout + z*M*N (fp32),
//         z==1 uses biasz (zeros) so bias is applied exactly once.
// EPI: 0 = bias->bf16 ; 1 = bias+GELU->bf16 ; 2 = bias->fp32
// ---------------------------------------------------------------------------
template <int BM, int EPI, bool SPLIT2>
__global__ __launch_bounds__(256)
void gemm_bt(const bf16_t* __restrict__ A, const bf16_t* __restrict__ B,
             const float* __restrict__ bias, const float* __restrict__ biasz,
             void* __restrict__ Cout, int M, int N, int K)
{
    constexpr int MI = BM / 32;
    __shared__ bf16_t sA[2][BM][32];
    __shared__ bf16_t sB[2][128][32];
    bf16_t* sAf = &sA[0][0][0];
    bf16_t* sBf = &sB[0][0][0];

    const int tid  = threadIdx.x;
    const int wave = tid >> 6;
    const int lane = tid & 63;
    const int g    = lane >> 4;
    const int c16  = lane & 15;
    const int wm   = (wave >> 1) * (BM / 2);
    const int wn   = (wave & 1) * 64;
    const int m0   = blockIdx.y * BM;
    const int n0   = blockIdx.x * 128;

    const int zz    = SPLIT2 ? blockIdx.z : 0;
    const int Keff  = SPLIT2 ? (K >> 1) : K;
    const int kbase = zz * Keff;
    const float* bptr = (SPLIT2 && zz) ? biasz : bias;

    const f32x4 fz = {0.f, 0.f, 0.f, 0.f};
    f32x4 acc[MI][4];
#pragma unroll
    for (int i = 0; i < MI; i++)
#pragma unroll
        for (int j = 0; j < 4; j++) acc[i][j] = fz;

    const int srow = tid >> 2;
    const int scol = (tid & 3) * 8;
    const bf16_t* pa = A + (size_t)(m0 + srow) * K + kbase + scol;
    const bf16_t* pb = B + (size_t)(n0 + srow) * K + kbase + scol;

    // prologue: tile 0 -> buf 0
#pragma unroll
    for (int i = 0; i < BM / 64; i++)
        gload16(pa + (size_t)i * 64 * K, sAf + i * 2048 + tid * 8);
#pragma unroll
    for (int i = 0; i < 2; i++)
        gload16(pb + (size_t)i * 64 * K, sBf + i * 2048 + tid * 8);

    const int NK = Keff >> 5;
    for (int kk = 0; kk < NK; ++kk) {
        const int cur = kk & 1;
        __syncthreads();                 // drains DMA for tile kk (vmcnt+lgkm)
        if (kk + 1 < NK) {               // issue tile kk+1 into other buffer
            const int k0 = (kk + 1) * 32;
            bf16_t* dA = sAf + (cur ^ 1) * (BM * 32);
            bf16_t* dB = sBf + (cur ^ 1) * 4096;
#pragma unroll
            for (int i = 0; i < BM / 64; i++)
                gload16(pa + (size_t)i * 64 * K + k0, dA + i * 2048 + tid * 8);
#pragma unroll
            for (int i = 0; i < 2; i++)
                gload16(pb + (size_t)i * 64 * K + k0, dB + i * 2048 + tid * 8);
        }

        bf16x8 af[MI], bfr[4];
#pragma unroll
        for (int i = 0; i < MI; i++)
            af[i] = *(const bf16x8*)&sA[cur][wm + i * 16 + c16][g * 8];
#pragma unroll
        for (int j = 0; j < 4; j++)
            bfr[j] = *(const bf16x8*)&sB[cur][wn + j * 16 + c16][g * 8];
#pragma unroll
        for (int mi = 0; mi < MI; mi++)
#pragma unroll
            for (int ni = 0; ni < 4; ni++)
                acc[mi][ni] = __builtin_amdgcn_mfma_f32_16x16x32_bf16(
                    af[mi], bfr[ni], acc[mi][ni], 0, 0, 0);
    }

    float* outf = (float*)Cout + (size_t)zz * M * N;
#pragma unroll
    for (int mi = 0; mi < MI; mi++) {
#pragma unroll
        for (int ni = 0; ni < 4; ni++) {
            const int col = n0 + wn + ni * 16 + c16;
            const float bv = bptr[col];
#pragma unroll
            for (int r = 0; r < 4; r++) {
                const int row = m0 + wm + mi * 16 + g * 4 + r;
                float v = acc[mi][ni][r] + bv;
                if (EPI == 1) v = 0.5f * v * (1.f + erff(v * 0.70710678118654752f));
                if (EPI == 2)
                    outf[(size_t)row * N + col] = v;
                else
                    ((bf16_t*)Cout)[(size_t)row * N + col] = (bf16_t)v;
            }
        }
    }
}

// ---------------------------------------------------------------------------
// transpose V out of QKV into Vt[bh][64][2048], t-dim interleaved within each
// 32-chunk: pos = 2*(t%16) + (t/16)%2 (+32*(t/32)). MFMA k-sums are
// permutation-invariant per 32-half, so flash uses this order for V^T and P.
// ---------------------------------------------------------------------------
__global__ __launch_bounds__(256)
void transpose_v(const bf16_t* __restrict__ qkv, bf16_t* __restrict__ vt)
{
    __shared__ bf16_t st[64][72];
    const int t0 = blockIdx.x * 64;
    const int bh = blockIdx.y;
    const int b = bh >> 3, h = bh & 7;
    const int tid = threadIdx.x;

    for (int c = tid; c < 512; c += 256) {
        int r = c >> 3, cj = (c & 7) * 8;
        const bf16_t* src = qkv + ((size_t)(b * SEQ + t0 + r)) * 1536 + 1024 + h * 64 + cj;
        *(int4*)&st[r][cj] = *(const int4*)src;
    }
    __syncthreads();
    for (int c = tid; c < 512; c += 256) {
        int d = c >> 3, pj = (c & 7) * 8;
        alignas(16) bf16_t tmp[8];
#pragma unroll
        for (int j = 0; j < 8; j++) {
            int p = pj + j;
            int t = (p & 32) + ((p & 1) << 4) + ((p & 31) >> 1);   // inverse perm
            tmp[j] = st[t][d];
        }
        *(int4*)(vt + ((size_t)(bh * 64 + d)) * SEQ + t0 + pj) = *(const int4*)tmp;
    }
}

// ---------------------------------------------------------------------------
// Flash attention v7 (unchanged from R7): DMA staging, zero staging VGPRs.
// grid (SEQ/128, B*H) = (16,32), block 256 (4 waves x 32 q-rows).
// K/V double-buffered in UNPADDED [64][64] LDS, XOR-swizzled chunk placement.
// One barrier per iter; DMA for tile i+1 issued right after tile i publishes.
// Q pre-scaled by (1/8)*log2(e) -> P = exp2(S). Row-sum l via sOnes block.
// ---------------------------------------------------------------------------
__global__ __launch_bounds__(256)
void flash_attn(const bf16_t* __restrict__ qkv, const bf16_t* __restrict__ vt,
                bf16_t* __restrict__ ctx)
{
    __shared__ bf16_t sK[2][64][64];    // 16 KB
    __shared__ bf16_t sVt[2][64][64];   // 16 KB
    __shared__ bf16_t sOnes[16][72];    // 2.25 KB ; row 0 = ones, rest zero
    __shared__ bf16_t sP[128][72];      // 18 KB

    const int bh = blockIdx.y;
    const int b = bh >> 3, h = bh & 7;
    const int q0 = blockIdx.x * 128;
    const int tid = threadIdx.x;
    const int wave = tid >> 6, lane = tid & 63;
    const int g = lane >> 4, c16 = lane & 15;

    for (int c = tid; c < 16 * 72; c += 256)
        sOnes[c / 72][c % 72] = (c / 72 == 0) ? (bf16_t)1.0f : (bf16_t)0.0f;

    const float qscale = 0.125f * 1.4426950408889634f;   // 1/sqrt(64) * log2(e)
    bf16x8 aq[2][2];
#pragma unroll
    for (int mf = 0; mf < 2; mf++)
#pragma unroll
        for (int ks = 0; ks < 2; ks++) {
            bf16x8 v = *(const bf16x8*)(qkv +
                ((size_t)(b * SEQ + q0 + wave * 32 + mf * 16 + c16)) * 1536 +
                h * 64 + ks * 32 + g * 8);
#pragma unroll
            for (int j = 0; j < 8; j++) v[j] = (bf16_t)((float)v[j] * qscale);
            aq[mf][ks] = v;
        }

    const f32x4 fz = {0.f, 0.f, 0.f, 0.f};
    f32x4 acc_o[2][5];
#pragma unroll
    for (int mf = 0; mf < 2; mf++)
#pragma unroll
        for (int nd = 0; nd < 5; nd++) acc_o[mf][nd] = fz;

    const int f0 = tid,        r0 = f0 >> 3, l0 = (f0 & 7) ^ (r0 & 7);
    const int f1 = tid + 256,  r1 = f1 >> 3, l1 = (f1 & 7) ^ (r1 & 7);
    const bf16_t* gK0 = qkv + ((size_t)(b * SEQ + r0)) * 1536 + 512 + h * 64 + l0 * 8;
    const bf16_t* gK1 = qkv + ((size_t)(b * SEQ + r1)) * 1536 + 512 + h * 64 + l1 * 8;
    const bf16_t* gV0 = vt + ((size_t)(bh * 64 + r0)) * SEQ + l0 * 8;
    const bf16_t* gV1 = vt + ((size_t)(bh * 64 + r1)) * SEQ + l1 * 8;
    bf16_t* lK = &sK[0][0][0];
    bf16_t* lV = &sVt[0][0][0];

    gload16(gK0, lK + f0 * 8);
    gload16(gK1, lK + f1 * 8);
    gload16(gV0, lV + f0 * 8);
    gload16(gV1, lV + f1 * 8);

    for (int it = 0; it < 32; ++it) {
        const int cur = it & 1;
        __syncthreads();
        if (it < 31) {
            const size_t kv = (size_t)(it + 1) * 64;
            const int bo = (cur ^ 1) * 4096;
            gload16(gK0 + kv * 1536, lK + bo + f0 * 8);
            gload16(gK1 + kv * 1536, lK + bo + f1 * 8);
            gload16(gV0 + kv,        lV + bo + f0 * 8);
            gload16(gV1 + kv,        lV + bo + f1 * 8);
        }

        f32x4 accs[2][4];
#pragma unroll
        for (int mf = 0; mf < 2; mf++)
#pragma unroll
            for (int n = 0; n < 4; n++) accs[mf][n] = fz;
#pragma unroll
        for (int ks = 0; ks < 2; ks++)
#pragma unroll
            for (int n = 0; n < 4; n++) {
                const int pc = ((ks * 4 + g) ^ (c16 & 7)) * 8;
                bf16x8 bk = *(const bf16x8*)&sK[cur][n * 16 + c16][pc];
                accs[0][n] = __builtin_amdgcn_mfma_f32_16x16x32_bf16(aq[0][ks], bk, accs[0][n], 0, 0, 0);
                accs[1][n] = __builtin_amdgcn_mfma_f32_16x16x32_bf16(aq[1][ks], bk, accs[1][n], 0, 0, 0);
            }

#pragma unroll
        for (int mf = 0; mf < 2; mf++)
#pragma unroll
            for (int r = 0; r < 4; r++) {
                const int prow = wave * 32 + mf * 16 + g * 4 + r;
#pragma unroll
                for (int ks = 0; ks < 2; ks++) {
                    bf16x2 pp;
                    pp[0] = (bf16_t)__builtin_amdgcn_exp2f(accs[mf][2 * ks][r]);
                    pp[1] = (bf16_t)__builtin_amdgcn_exp2f(accs[mf][2 * ks + 1][r]);
                    *(bf16x2*)&sP[prow][ks * 32 + 2 * c16] = pp;
                }
            }

#pragma unroll
        for (int ks = 0; ks < 2; ks++) {
            bf16x8 ap0 = *(const bf16x8*)&sP[wave * 32 + c16][ks * 32 + g * 8];
            bf16x8 ap1 = *(const bf16x8*)&sP[wave * 32 + 16 + c16][ks * 32 + g * 8];
#pragma unroll
            for (int nd = 0; nd < 5; nd++) {
                bf16x8 vb;
                if (nd < 4) {
                    const int pc = ((ks * 4 + g) ^ (c16 & 7)) * 8;
                    vb = *(const bf16x8*)&sVt[cur][nd * 16 + c16][pc];
                } else {
                    vb = *(const bf16x8*)&sOnes[c16][ks * 32 + g * 8];
                }
                acc_o[0][nd] = __builtin_amdgcn_mfma_f32_16x16x32_bf16(ap0, vb, acc_o[0][nd], 0, 0, 0);
                acc_o[1][nd] = __builtin_amdgcn_mfma_f32_16x16x32_bf16(ap1, vb, acc_o[1][nd], 0, 0, 0);
            }
        }
    }

#pragma unroll
    for (int mf = 0; mf < 2; mf++)
#pragma unroll
        for (int r = 0; r < 4; r++) {
            float lv  = __shfl(acc_o[mf][4][r], lane & 48, 64);
            float inv = 1.0f / lv;
            const size_t base =
                ((size_t)(b * SEQ + q0 + wave * 32 + mf * 16 + g * 4 + r)) * 512 + h * 64;
#pragma unroll
            for (int nd = 0; nd < 4; nd++)
                ctx[base + nd * 16 + c16] = (bf16_t)(acc_o[mf][nd][r] * inv);
        }
}

// ---------------------------------------------------------------------------
// out = LayerNorm(a + b + c) * gamma + beta ; optional bf16 copy
// ---------------------------------------------------------------------------
__global__ __launch_bounds__(256)
void add_ln3(const float* __restrict__ a, const float* __restrict__ b,
             const float* __restrict__ c,
             const float* __restrict__ gamma, const float* __restrict__ beta,
             float* __restrict__ outf, bf16_t* __restrict__ outb)
{
    const int row  = blockIdx.x * 4 + (threadIdx.x >> 6);
    const int lane = threadIdx.x & 63;
    const size_t base = (size_t)row * 512 + lane * 8;

    float v[8];
#pragma unroll
    for (int h = 0; h < 2; h++) {
        float4 av = *(const float4*)(a + base + h * 4);
        float4 bv = *(const float4*)(b + base + h * 4);
        float4 cv = *(const float4*)(c + base + h * 4);
        v[h * 4 + 0] = av.x + bv.x + cv.x;
        v[h * 4 + 1] = av.y + bv.y + cv.y;
        v[h * 4 + 2] = av.z + bv.z + cv.z;
        v[h * 4 + 3] = av.w + bv.w + cv.w;
    }

    float s = 0.f;
#pragma unroll
    for (int i = 0; i < 8; i++) s += v[i];
#pragma unroll
    for (int off = 32; off > 0; off >>= 1) s += __shfl_xor(s, off);
    const float mu = s * (1.f / 512.f);

    float q = 0.f;
#pragma unroll
    for (int i = 0; i < 8; i++) { float d = v[i] - mu; q += d * d; }
#pragma unroll
    for (int off = 32; off > 0; off >>= 1) q += __shfl_xor(q, off);
    const float rstd = rsqrtf(q * (1.f / 512.f) + 1e-5f);

    float4 g0 = *(const float4*)(gamma + lane * 8);
    float4 g1 = *(const float4*)(gamma + lane * 8 + 4);
    float4 e0 = *(const float4*)(beta + lane * 8);
    float4 e1 = *(const float4*)(beta + lane * 8 + 4);
    const float gg[8] = {g0.x, g0.y, g0.z, g0.w, g1.x, g1.y, g1.z, g1.w};
    const float ee[8] = {e0.x, e0.y, e0.z, e0.w, e1.x, e1.y, e1.z, e1.w};

    float o[8];
#pragma unroll
    for (int i = 0; i < 8; i++) o[i] = (v[i] - mu) * rstd * gg[i] + ee[i];

    *(float4*)(outf + base)     = make_float4(o[0], o[1], o[2], o[3]);
    *(float4*)(outf + base + 4) = make_float4(o[4], o[5], o[6], o[7]);
    if (outb) {
        alignas(16) bf16_t ob[8];
#pragma unroll
        for (int i = 0; i < 8; i++) ob[i] = (bf16_t)o[i];
        *(int4*)(outb + base) = *(const int4*)ob;
    }
}

// ---------------------------------------------------------------------------
extern "C" void kernel_launch(void* const* d_in, const int* in_sizes, int n_in,
                              void* d_out, int out_size, void* d_ws, size_t ws_size,
                              hipStream_t stream)
{
    const float* src = (const float*)d_in[0];
    const float* Wq  = (const float*)d_in[1];  const float* bq  = (const float*)d_in[2];
    const float* Wk  = (const float*)d_in[3];  const float* bk  = (const float*)d_in[4];
    const float* Wv  = (const float*)d_in[5];  const float* bv  = (const float*)d_in[6];
    const float* Wo  = (const float*)d_in[7];  const float* bo  = (const float*)d_in[8];
    const float* W1  = (const float*)d_in[9];  const float* b1  = (const float*)d_in[10];
    const float* W2  = (const float*)d_in[11]; const float* b2  = (const float*)d_in[12];
    const float* g1  = (const float*)d_in[13]; const float* be1 = (const float*)d_in[14];
    const float* g2  = (const float*)d_in[15]; const float* be2 = (const float*)d_in[16];
    float* out = (float*)d_out;

    char* ws = (char*)d_ws;
    size_t off = 0;
    auto alloc = [&](size_t bytes) -> void* {
        void* p = ws + off;
        off = (off + bytes + 255) & ~(size_t)255;
        return p;
    };

    bf16_t* Xb    = (bf16_t*)alloc((size_t)TOKENS * 512 * 2);
    bf16_t* Wqkvb = (bf16_t*)alloc((size_t)1536 * 512 * 2);
    bf16_t* Wob   = (bf16_t*)alloc((size_t)512 * 512 * 2);
    bf16_t* W1b   = (bf16_t*)alloc((size_t)2048 * 512 * 2);
    bf16_t* W2b   = (bf16_t*)alloc((size_t)512 * 2048 * 2);
    float*  bqkv  = (float*)alloc(1536 * 4);
    float*  zbias = (float*)alloc(512 * 4);
    bf16_t* QKV   = (bf16_t*)alloc((size_t)TOKENS * 1536 * 2);  // contiguous with Vt
    bf16_t* Vt    = (bf16_t*)alloc((size_t)32 * 64 * SEQ * 2);
    bf16_t* CTX   = (bf16_t*)alloc((size_t)TOKENS * 512 * 2);
    float*  ATTa  = (float*)alloc((size_t)TOKENS * 512 * 4);    // contiguous with ATTb
    float*  ATTb  = (float*)alloc((size_t)TOKENS * 512 * 4);
    float*  X1    = (float*)alloc((size_t)TOKENS * 512 * 4);
    bf16_t* X1b   = (bf16_t*)alloc((size_t)TOKENS * 512 * 2);

    bf16_t* H    = QKV;    // alias: QKV+Vt (33.55 MB exactly) dead after flash
    float*  FFNa = ATTa;   // alias: ATTa/ATTb dead after ln1 (contiguous pair)
    float*  FFNb = ATTb;

    cvt_weights<<<7170, 256, 0, stream>>>(src, Wq, Wk, Wv, Wo, W1, W2, bq, bk, bv,
                                          Xb, Wqkvb, Wob, W1b, W2b, bqkv, zbias);

    // fused QKV projection
    gemm_bt<128, 0, false><<<dim3(12, 64), 256, 0, stream>>>(
        Xb, Wqkvb, bqkv, zbias, QKV, TOKENS, 1536, 512);

    transpose_v<<<dim3(32, 32), 256, 0, stream>>>(QKV, Vt);
    flash_attn<<<dim3(16, 32), 256, 0, stream>>>(QKV, Vt, CTX);

    // Wo projection, split-K=2 -> ATTa/ATTb partials
    gemm_bt<64, 2, true><<<dim3(4, 128, 2), 256, 0, stream>>>(
        CTX, Wob, bo, zbias, ATTa, TOKENS, 512, 512);

    add_ln3<<<2048, 256, 0, stream>>>(src, ATTa, ATTb, g1, be1, X1, X1b);

    gemm_bt<128, 1, false><<<dim3(16, 64), 256, 0, stream>>>(
        X1b, W1b, b1, zbias, H, TOKENS, 2048, 512);

    // W2, split-K=2 -> FFNa/FFNb partials
    gemm_bt<64, 2, true><<<dim3(4, 128, 2), 256, 0, stream>>>(
        H, W2b, b2, zbias, FFNa, TOKENS, 512, 2048);

    add_ln3<<<2048, 256, 0, stream>>>(X1, FFNa, FFNb, g2, be2, out, nullptr);
}

// Round 9
// 286.110 us; speedup vs baseline: 1.6117x; 1.0363x over previous
//
#include <hip/hip_runtime.h>
#include <hip/hip_bf16.h>
#include <hip/hip_fp16.h>
#include <math.h>

// ---------------------------------------------------------------------------
typedef __bf16 bf16_t;
typedef __bf16 bf16x8 __attribute__((ext_vector_type(8)));
typedef __bf16 bf16x2 __attribute__((ext_vector_type(2)));
typedef float  f32x4  __attribute__((ext_vector_type(4)));

#define D_MODEL 512
#define NHEAD   8
#define HD      64
#define D_FF    2048
#define TOKENS  8192   // 4 * 2048
#define SEQ     2048
#define BATCH   4

// async global->LDS, 16B per lane; LDS dest = wave-uniform base + lane*16
__device__ __forceinline__ void gload16(const bf16_t* g, bf16_t* l)
{
    __builtin_amdgcn_global_load_lds(
        (const __attribute__((address_space(1))) void*)g,
        (__attribute__((address_space(3))) void*)l,
        16, 0, 0);
}

__device__ __forceinline__ void cvt4(const float* s, bf16_t* d)
{
    float4 v = *(const float4*)s;
    alignas(8) bf16_t t[4] = {(bf16_t)v.x, (bf16_t)v.y, (bf16_t)v.z, (bf16_t)v.w};
    *(uint2*)d = *(const uint2*)t;
}

// ---------------------------------------------------------------------------
// src + all weight conversions + bias concat + zero-bias fill in ONE kernel.
// ---------------------------------------------------------------------------
__global__ void cvt_weights(const float* __restrict__ src,
                            const float* __restrict__ Wq, const float* __restrict__ Wk,
                            const float* __restrict__ Wv, const float* __restrict__ Wo,
                            const float* __restrict__ W1, const float* __restrict__ W2,
                            const float* __restrict__ bq, const float* __restrict__ bk,
                            const float* __restrict__ bv,
                            bf16_t* __restrict__ Xb,
                            bf16_t* __restrict__ Wqkvb, bf16_t* __restrict__ Wob,
                            bf16_t* __restrict__ W1b, bf16_t* __restrict__ W2b,
                            float* __restrict__ bqkv, float* __restrict__ zbias)
{
    int i = blockIdx.x * 256 + threadIdx.x;   // one thread = 4 elements
    if (i < 1048576) { cvt4(src + (size_t)i * 4, Xb + (size_t)i * 4); return; }
    i -= 1048576;
    if (i < 65536)        cvt4(Wq + (size_t)i * 4,            Wqkvb + (size_t)i * 4);
    else if (i < 131072)  cvt4(Wk + (size_t)(i - 65536) * 4,  Wqkvb + (size_t)i * 4);
    else if (i < 196608)  cvt4(Wv + (size_t)(i - 131072) * 4, Wqkvb + (size_t)i * 4);
    else if (i < 262144)  cvt4(Wo + (size_t)(i - 196608) * 4, Wob + (size_t)(i - 196608) * 4);
    else if (i < 524288)  cvt4(W1 + (size_t)(i - 262144) * 4, W1b + (size_t)(i - 262144) * 4);
    else if (i < 786432)  cvt4(W2 + (size_t)(i - 524288) * 4, W2b + (size_t)(i - 524288) * 4);
    else if (i < 786816) {
        int j = i - 786432;   // 0..383 -> 1536 bias floats
        const float* s = (j < 128) ? bq + j * 4 : (j < 256) ? bk + (j - 128) * 4
                                                            : bv + (j - 256) * 4;
        *(float4*)(bqkv + (j & 127) * 4 + (j >> 7) * 512) = *(const float4*)s;
    } else if (i < 786944) {
        int j = i - 786816;   // 0..127 -> 512 zero floats
        *(float4*)(zbias + j * 4) = make_float4(0.f, 0.f, 0.f, 0.f);
    }
}

// ---------------------------------------------------------------------------
// GEMM v2: C[M,N] = A[M,K] @ B[N,K]^T + bias, bf16 in, fp32 accum.
// BM x 128 tile, BK=32, 256 threads. Double-buffered global_load_lds, single
// barrier per iter (DMA for tile k+1 issued right after tile k publishes).
// SPLIT2: gridDim.z==2, each z-half does K/2, writes fp16 partials at
//         Cout + z*M*N; z==1 uses biasz (zeros) so bias applies once.
// EPI: 0 = bias->bf16 ; 1 = bias+GELU->bf16 ; 2 = bias->fp16 partial
// ---------------------------------------------------------------------------
template <int BM, int EPI, bool SPLIT2>
__global__ __launch_bounds__(256)
void gemm_bt(const bf16_t* __restrict__ A, const bf16_t* __restrict__ B,
             const float* __restrict__ bias, const float* __restrict__ biasz,
             void* __restrict__ Cout, int M, int N, int K)
{
    constexpr int MI = BM / 32;
    __shared__ bf16_t sA[2][BM][32];
    __shared__ bf16_t sB[2][128][32];
    bf16_t* sAf = &sA[0][0][0];
    bf16_t* sBf = &sB[0][0][0];

    const int tid  = threadIdx.x;
    const int wave = tid >> 6;
    const int lane = tid & 63;
    const int g    = lane >> 4;
    const int c16  = lane & 15;
    const int wm   = (wave >> 1) * (BM / 2);
    const int wn   = (wave & 1) * 64;
    const int m0   = blockIdx.y * BM;
    const int n0   = blockIdx.x * 128;

    const int zz    = SPLIT2 ? blockIdx.z : 0;
    const int Keff  = SPLIT2 ? (K >> 1) : K;
    const int kbase = zz * Keff;
    const float* bptr = (SPLIT2 && zz) ? biasz : bias;

    const f32x4 fz = {0.f, 0.f, 0.f, 0.f};
    f32x4 acc[MI][4];
#pragma unroll
    for (int i = 0; i < MI; i++)
#pragma unroll
        for (int j = 0; j < 4; j++) acc[i][j] = fz;

    const int srow = tid >> 2;
    const int scol = (tid & 3) * 8;
    const bf16_t* pa = A + (size_t)(m0 + srow) * K + kbase + scol;
    const bf16_t* pb = B + (size_t)(n0 + srow) * K + kbase + scol;

    // prologue: tile 0 -> buf 0
#pragma unroll
    for (int i = 0; i < BM / 64; i++)
        gload16(pa + (size_t)i * 64 * K, sAf + i * 2048 + tid * 8);
#pragma unroll
    for (int i = 0; i < 2; i++)
        gload16(pb + (size_t)i * 64 * K, sBf + i * 2048 + tid * 8);

    const int NK = Keff >> 5;
    for (int kk = 0; kk < NK; ++kk) {
        const int cur = kk & 1;
        __syncthreads();                 // drains DMA for tile kk
        if (kk + 1 < NK) {               // issue tile kk+1 into other buffer
            const int k0 = (kk + 1) * 32;
            bf16_t* dA = sAf + (cur ^ 1) * (BM * 32);
            bf16_t* dB = sBf + (cur ^ 1) * 4096;
#pragma unroll
            for (int i = 0; i < BM / 64; i++)
                gload16(pa + (size_t)i * 64 * K + k0, dA + i * 2048 + tid * 8);
#pragma unroll
            for (int i = 0; i < 2; i++)
                gload16(pb + (size_t)i * 64 * K + k0, dB + i * 2048 + tid * 8);
        }

        bf16x8 af[MI], bfr[4];
#pragma unroll
        for (int i = 0; i < MI; i++)
            af[i] = *(const bf16x8*)&sA[cur][wm + i * 16 + c16][g * 8];
#pragma unroll
        for (int j = 0; j < 4; j++)
            bfr[j] = *(const bf16x8*)&sB[cur][wn + j * 16 + c16][g * 8];
#pragma unroll
        for (int mi = 0; mi < MI; mi++)
#pragma unroll
            for (int ni = 0; ni < 4; ni++)
                acc[mi][ni] = __builtin_amdgcn_mfma_f32_16x16x32_bf16(
                    af[mi], bfr[ni], acc[mi][ni], 0, 0, 0);
    }

    __half* outh = (__half*)Cout + (size_t)zz * M * N;
#pragma unroll
    for (int mi = 0; mi < MI; mi++) {
#pragma unroll
        for (int ni = 0; ni < 4; ni++) {
            const int col = n0 + wn + ni * 16 + c16;
            const float bv = bptr[col];
#pragma unroll
            for (int r = 0; r < 4; r++) {
                const int row = m0 + wm + mi * 16 + g * 4 + r;
                float v = acc[mi][ni][r] + bv;
                if (EPI == 1) v = 0.5f * v * (1.f + erff(v * 0.70710678118654752f));
                if (EPI == 2)
                    outh[(size_t)row * N + col] = (__half)v;
                else
                    ((bf16_t*)Cout)[(size_t)row * N + col] = (bf16_t)v;
            }
        }
    }
}

// ---------------------------------------------------------------------------
// transpose V out of QKV into Vt[bh][64][2048], t-dim interleaved within each
// 32-chunk: pos = 2*(t%16) + (t/16)%2 (+32*(t/32)). MFMA k-sums are
// permutation-invariant per 32-half, so flash uses this order for V^T and P.
// ---------------------------------------------------------------------------
__global__ __launch_bounds__(256)
void transpose_v(const bf16_t* __restrict__ qkv, bf16_t* __restrict__ vt)
{
    __shared__ bf16_t st[64][72];
    const int t0 = blockIdx.x * 64;
    const int bh = blockIdx.y;
    const int b = bh >> 3, h = bh & 7;
    const int tid = threadIdx.x;

    for (int c = tid; c < 512; c += 256) {
        int r = c >> 3, cj = (c & 7) * 8;
        const bf16_t* src = qkv + ((size_t)(b * SEQ + t0 + r)) * 1536 + 1024 + h * 64 + cj;
        *(int4*)&st[r][cj] = *(const int4*)src;
    }
    __syncthreads();
    for (int c = tid; c < 512; c += 256) {
        int d = c >> 3, pj = (c & 7) * 8;
        alignas(16) bf16_t tmp[8];
#pragma unroll
        for (int j = 0; j < 8; j++) {
            int p = pj + j;
            int t = (p & 32) + ((p & 1) << 4) + ((p & 31) >> 1);   // inverse perm
            tmp[j] = st[t][d];
        }
        *(int4*)(vt + ((size_t)(bh * 64 + d)) * SEQ + t0 + pj) = *(const int4*)tmp;
    }
}

// ---------------------------------------------------------------------------
// Flash attention v8: 48 KB LDS -> 3 blocks/CU (3 barrier domains).
// grid (SEQ/128, B*H) = (16,32), block 256 (4 waves x 32 q-rows).
// K/V double-buffered UNPADDED [64][64], XOR-swizzled chunk placement
// (phys16B = logical ^ (row&7)) via global_load_lds DMA. sP now also
// unpadded+swizzled (write-side 2-way = free; read phases quad-uniform).
// Ones-column B-fragment is (c16==0)?1:0 -- a register constant, no LDS.
// One barrier/iter; DMA for tile i+1 issued right after tile i publishes.
// Q pre-scaled by (1/8)*log2(e) -> P = exp2(S).
// ---------------------------------------------------------------------------
__global__ __launch_bounds__(256)
void flash_attn(const bf16_t* __restrict__ qkv, const bf16_t* __restrict__ vt,
                bf16_t* __restrict__ ctx)
{
    __shared__ bf16_t sK[2][64][64];    // 16 KB
    __shared__ bf16_t sVt[2][64][64];   // 16 KB
    __shared__ bf16_t sP[128][64];      // 16 KB, swizzled

    const int bh = blockIdx.y;
    const int b = bh >> 3, h = bh & 7;
    const int q0 = blockIdx.x * 128;
    const int tid = threadIdx.x;
    const int wave = tid >> 6, lane = tid & 63;
    const int g = lane >> 4, c16 = lane & 15;

    const float qscale = 0.125f * 1.4426950408889634f;   // 1/sqrt(64) * log2(e)
    bf16x8 aq[2][2];
#pragma unroll
    for (int mf = 0; mf < 2; mf++)
#pragma unroll
        for (int ks = 0; ks < 2; ks++) {
            bf16x8 v = *(const bf16x8*)(qkv +
                ((size_t)(b * SEQ + q0 + wave * 32 + mf * 16 + c16)) * 1536 +
                h * 64 + ks * 32 + g * 8);
#pragma unroll
            for (int j = 0; j < 8; j++) v[j] = (bf16_t)((float)v[j] * qscale);
            aq[mf][ks] = v;
        }

    // ones-column fragment: row 64 of extended V^T is ones, 65..79 zero
    bf16x8 vb_ones;
    {
        const bf16_t o = (bf16_t)((c16 == 0) ? 1.0f : 0.0f);
#pragma unroll
        for (int j = 0; j < 8; j++) vb_ones[j] = o;
    }

    const f32x4 fz = {0.f, 0.f, 0.f, 0.f};
    f32x4 acc_o[2][5];
#pragma unroll
    for (int mf = 0; mf < 2; mf++)
#pragma unroll
        for (int nd = 0; nd < 5; nd++) acc_o[mf][nd] = fz;

    const int f0 = tid,        r0 = f0 >> 3, l0 = (f0 & 7) ^ (r0 & 7);
    const int f1 = tid + 256,  r1 = f1 >> 3, l1 = (f1 & 7) ^ (r1 & 7);
    const bf16_t* gK0 = qkv + ((size_t)(b * SEQ + r0)) * 1536 + 512 + h * 64 + l0 * 8;
    const bf16_t* gK1 = qkv + ((size_t)(b * SEQ + r1)) * 1536 + 512 + h * 64 + l1 * 8;
    const bf16_t* gV0 = vt + ((size_t)(bh * 64 + r0)) * SEQ + l0 * 8;
    const bf16_t* gV1 = vt + ((size_t)(bh * 64 + r1)) * SEQ + l1 * 8;
    bf16_t* lK = &sK[0][0][0];
    bf16_t* lV = &sVt[0][0][0];

    gload16(gK0, lK + f0 * 8);
    gload16(gK1, lK + f1 * 8);
    gload16(gV0, lV + f0 * 8);
    gload16(gV1, lV + f1 * 8);

    for (int it = 0; it < 32; ++it) {
        const int cur = it & 1;
        __syncthreads();
        if (it < 31) {
            const size_t kv = (size_t)(it + 1) * 64;
            const int bo = (cur ^ 1) * 4096;
            gload16(gK0 + kv * 1536, lK + bo + f0 * 8);
            gload16(gK1 + kv * 1536, lK + bo + f1 * 8);
            gload16(gV0 + kv,        lV + bo + f0 * 8);
            gload16(gV1 + kv,        lV + bo + f1 * 8);
        }

        f32x4 accs[2][4];
#pragma unroll
        for (int mf = 0; mf < 2; mf++)
#pragma unroll
            for (int n = 0; n < 4; n++) accs[mf][n] = fz;
#pragma unroll
        for (int ks = 0; ks < 2; ks++)
#pragma unroll
            for (int n = 0; n < 4; n++) {
                const int pc = ((ks * 4 + g) ^ (c16 & 7)) * 8;
                bf16x8 bk = *(const bf16x8*)&sK[cur][n * 16 + c16][pc];
                accs[0][n] = __builtin_amdgcn_mfma_f32_16x16x32_bf16(aq[0][ks], bk, accs[0][n], 0, 0, 0);
                accs[1][n] = __builtin_amdgcn_mfma_f32_16x16x32_bf16(aq[1][ks], bk, accs[1][n], 0, 0, 0);
            }

        // P = 2^S -> swizzled packed-pair stores (interleaved-t order)
#pragma unroll
        for (int mf = 0; mf < 2; mf++)
#pragma unroll
            for (int r = 0; r < 4; r++) {
                const int prow = wave * 32 + mf * 16 + g * 4 + r;
#pragma unroll
                for (int ks = 0; ks < 2; ks++) {
                    bf16x2 pp;
                    pp[0] = (bf16_t)__builtin_amdgcn_exp2f(accs[mf][2 * ks][r]);
                    pp[1] = (bf16_t)__builtin_amdgcn_exp2f(accs[mf][2 * ks + 1][r]);
                    const int lc = ks * 4 + (c16 >> 2);
                    const int pc = ((lc ^ (prow & 7)) << 3) + ((2 * c16) & 7);
                    *(bf16x2*)&sP[prow][pc] = pp;
                }
            }

        // O += P @ [V | 1]  (sP rows wave-private; DS ops in-order per wave)
#pragma unroll
        for (int ks = 0; ks < 2; ks++) {
            const int rpc = ((ks * 4 + g) ^ (c16 & 7)) * 8;
            bf16x8 ap0 = *(const bf16x8*)&sP[wave * 32 + c16][rpc];
            bf16x8 ap1 = *(const bf16x8*)&sP[wave * 32 + 16 + c16][rpc];
#pragma unroll
            for (int nd = 0; nd < 5; nd++) {
                bf16x8 vb;
                if (nd < 4) {
                    const int pc = ((ks * 4 + g) ^ (c16 & 7)) * 8;
                    vb = *(const bf16x8*)&sVt[cur][nd * 16 + c16][pc];
                } else {
                    vb = vb_ones;
                }
                acc_o[0][nd] = __builtin_amdgcn_mfma_f32_16x16x32_bf16(ap0, vb, acc_o[0][nd], 0, 0, 0);
                acc_o[1][nd] = __builtin_amdgcn_mfma_f32_16x16x32_bf16(ap1, vb, acc_o[1][nd], 0, 0, 0);
            }
        }
    }

#pragma unroll
    for (int mf = 0; mf < 2; mf++)
#pragma unroll
        for (int r = 0; r < 4; r++) {
            float lv  = __shfl(acc_o[mf][4][r], lane & 48, 64);
            float inv = 1.0f / lv;
            const size_t base =
                ((size_t)(b * SEQ + q0 + wave * 32 + mf * 16 + g * 4 + r)) * 512 + h * 64;
#pragma unroll
            for (int nd = 0; nd < 4; nd++)
                ctx[base + nd * 16 + c16] = (bf16_t)(acc_o[mf][nd][r] * inv);
        }
}

// ---------------------------------------------------------------------------
// out = LayerNorm(a + b + c) * gamma + beta ; a fp32, b/c fp16 partials.
// ---------------------------------------------------------------------------
__global__ __launch_bounds__(256)
void add_ln3(const float* __restrict__ a, const __half* __restrict__ b,
             const __half* __restrict__ c,
             const float* __restrict__ gamma, const float* __restrict__ beta,
             float* __restrict__ outf, bf16_t* __restrict__ outb)
{
    const int row  = blockIdx.x * 4 + (threadIdx.x >> 6);
    const int lane = threadIdx.x & 63;
    const size_t base = (size_t)row * 512 + lane * 8;

    int4 braw = *(const int4*)(b + base);   // 8 halves
    int4 craw = *(const int4*)(c + base);
    const __half* bh = (const __half*)&braw;
    const __half* ch = (const __half*)&craw;

    float v[8];
#pragma unroll
    for (int hh = 0; hh < 2; hh++) {
        float4 av = *(const float4*)(a + base + hh * 4);
        v[hh * 4 + 0] = av.x + (float)bh[hh * 4 + 0] + (float)ch[hh * 4 + 0];
        v[hh * 4 + 1] = av.y + (float)bh[hh * 4 + 1] + (float)ch[hh * 4 + 1];
        v[hh * 4 + 2] = av.z + (float)bh[hh * 4 + 2] + (float)ch[hh * 4 + 2];
        v[hh * 4 + 3] = av.w + (float)bh[hh * 4 + 3] + (float)ch[hh * 4 + 3];
    }

    float s = 0.f;
#pragma unroll
    for (int i = 0; i < 8; i++) s += v[i];
#pragma unroll
    for (int off = 32; off > 0; off >>= 1) s += __shfl_xor(s, off);
    const float mu = s * (1.f / 512.f);

    float q = 0.f;
#pragma unroll
    for (int i = 0; i < 8; i++) { float d = v[i] - mu; q += d * d; }
#pragma unroll
    for (int off = 32; off > 0; off >>= 1) q += __shfl_xor(q, off);
    const float rstd = rsqrtf(q * (1.f / 512.f) + 1e-5f);

    float4 g0 = *(const float4*)(gamma + lane * 8);
    float4 g1 = *(const float4*)(gamma + lane * 8 + 4);
    float4 e0 = *(const float4*)(beta + lane * 8);
    float4 e1 = *(const float4*)(beta + lane * 8 + 4);
    const float gg[8] = {g0.x, g0.y, g0.z, g0.w, g1.x, g1.y, g1.z, g1.w};
    const float ee[8] = {e0.x, e0.y, e0.z, e0.w, e1.x, e1.y, e1.z, e1.w};

    float o[8];
#pragma unroll
    for (int i = 0; i < 8; i++) o[i] = (v[i] - mu) * rstd * gg[i] + ee[i];

    *(float4*)(outf + base)     = make_float4(o[0], o[1], o[2], o[3]);
    *(float4*)(outf + base + 4) = make_float4(o[4], o[5], o[6], o[7]);
    if (outb) {
        alignas(16) bf16_t ob[8];
#pragma unroll
        for (int i = 0; i < 8; i++) ob[i] = (bf16_t)o[i];
        *(int4*)(outb + base) = *(const int4*)ob;
    }
}

// ---------------------------------------------------------------------------
extern "C" void kernel_launch(void* const* d_in, const int* in_sizes, int n_in,
                              void* d_out, int out_size, void* d_ws, size_t ws_size,
                              hipStream_t stream)
{
    const float* src = (const float*)d_in[0];
    const float* Wq  = (const float*)d_in[1];  const float* bq  = (const float*)d_in[2];
    const float* Wk  = (const float*)d_in[3];  const float* bk  = (const float*)d_in[4];
    const float* Wv  = (const float*)d_in[5];  const float* bv  = (const float*)d_in[6];
    const float* Wo  = (const float*)d_in[7];  const float* bo  = (const float*)d_in[8];
    const float* W1  = (const float*)d_in[9];  const float* b1  = (const float*)d_in[10];
    const float* W2  = (const float*)d_in[11]; const float* b2  = (const float*)d_in[12];
    const float* g1  = (const float*)d_in[13]; const float* be1 = (const float*)d_in[14];
    const float* g2  = (const float*)d_in[15]; const float* be2 = (const float*)d_in[16];
    float* out = (float*)d_out;

    char* ws = (char*)d_ws;
    size_t off = 0;
    auto alloc = [&](size_t bytes) -> void* {
        void* p = ws + off;
        off = (off + bytes + 255) & ~(size_t)255;
        return p;
    };

    bf16_t* Xb    = (bf16_t*)alloc((size_t)TOKENS * 512 * 2);
    bf16_t* Wqkvb = (bf16_t*)alloc((size_t)1536 * 512 * 2);
    bf16_t* Wob   = (bf16_t*)alloc((size_t)512 * 512 * 2);
    bf16_t* W1b   = (bf16_t*)alloc((size_t)2048 * 512 * 2);
    bf16_t* W2b   = (bf16_t*)alloc((size_t)512 * 2048 * 2);
    float*  bqkv  = (float*)alloc(1536 * 4);
    float*  zbias = (float*)alloc(512 * 4);
    bf16_t* QKV   = (bf16_t*)alloc((size_t)TOKENS * 1536 * 2);  // contiguous with Vt
    bf16_t* Vt    = (bf16_t*)alloc((size_t)32 * 64 * SEQ * 2);
    bf16_t* CTX   = (bf16_t*)alloc((size_t)TOKENS * 512 * 2);
    __half* ATTa  = (__half*)alloc((size_t)TOKENS * 512 * 2);   // contiguous with ATTb
    __half* ATTb  = (__half*)alloc((size_t)TOKENS * 512 * 2);
    float*  X1    = (float*)alloc((size_t)TOKENS * 512 * 4);
    bf16_t* X1b   = (bf16_t*)alloc((size_t)TOKENS * 512 * 2);

    bf16_t* H    = QKV;    // alias: QKV+Vt (33.55 MB exactly) dead after flash
    __half* FFNa = ATTa;   // alias: ATTa/ATTb dead after ln1 (contiguous pair)
    __half* FFNb = ATTb;

    cvt_weights<<<7170, 256, 0, stream>>>(src, Wq, Wk, Wv, Wo, W1, W2, bq, bk, bv,
                                          Xb, Wqkvb, Wob, W1b, W2b, bqkv, zbias);

    // fused QKV projection
    gemm_bt<128, 0, false><<<dim3(12, 64), 256, 0, stream>>>(
        Xb, Wqkvb, bqkv, zbias, QKV, TOKENS, 1536, 512);

    transpose_v<<<dim3(32, 32), 256, 0, stream>>>(QKV, Vt);
    flash_attn<<<dim3(16, 32), 256, 0, stream>>>(QKV, Vt, CTX);

    // Wo projection, split-K=2 -> fp16 partials ATTa/ATTb
    gemm_bt<64, 2, true><<<dim3(4, 128, 2), 256, 0, stream>>>(
        CTX, Wob, bo, zbias, ATTa, TOKENS, 512, 512);

    add_ln3<<<2048, 256, 0, stream>>>(src, ATTa, ATTb, g1, be1, X1, X1b);

    gemm_bt<128, 1, false><<<dim3(16, 64), 256, 0, stream>>>(
        X1b, W1b, b1, zbias, H, TOKENS, 2048, 512);

    // W2, split-K=2 -> fp16 partials FFNa/FFNb
    gemm_bt<64, 2, true><<<dim3(4, 128, 2), 256, 0, stream>>>(
        H, W2b, b2, zbias, FFNa, TOKENS, 512, 2048);

    add_ln3<<<2048, 256, 0, stream>>>(X1, FFNa, FFNb, g2, be2, out, nullptr);
}

// Round 10
// 281.277 us; speedup vs baseline: 1.6394x; 1.0172x over previous
//
#include <hip/hip_runtime.h>
#include <hip/hip_bf16.h>
#include <hip/hip_fp16.h>
#include <math.h>

// ---------------------------------------------------------------------------
typedef __bf16 bf16_t;
typedef __bf16 bf16x8 __attribute__((ext_vector_type(8)));
typedef __bf16 bf16x2 __attribute__((ext_vector_type(2)));
typedef float  f32x4  __attribute__((ext_vector_type(4)));

#define D_MODEL 512
#define NHEAD   8
#define HD      64
#define D_FF    2048
#define TOKENS  8192   // 4 * 2048
#define SEQ     2048
#define BATCH   4

// async global->LDS, 16B per lane; LDS dest = wave-uniform base + lane*16
__device__ __forceinline__ void gload16(const bf16_t* g, bf16_t* l)
{
    __builtin_amdgcn_global_load_lds(
        (const __attribute__((address_space(1))) void*)g,
        (__attribute__((address_space(3))) void*)l,
        16, 0, 0);
}

__device__ __forceinline__ void cvt4(const float* s, bf16_t* d)
{
    float4 v = *(const float4*)s;
    alignas(8) bf16_t t[4] = {(bf16_t)v.x, (bf16_t)v.y, (bf16_t)v.z, (bf16_t)v.w};
    *(uint2*)d = *(const uint2*)t;
}

// ---------------------------------------------------------------------------
// src + all weight conversions + bias concat + zero-bias fill in ONE kernel.
// ---------------------------------------------------------------------------
__global__ void cvt_weights(const float* __restrict__ src,
                            const float* __restrict__ Wq, const float* __restrict__ Wk,
                            const float* __restrict__ Wv, const float* __restrict__ Wo,
                            const float* __restrict__ W1, const float* __restrict__ W2,
                            const float* __restrict__ bq, const float* __restrict__ bk,
                            const float* __restrict__ bv,
                            bf16_t* __restrict__ Xb,
                            bf16_t* __restrict__ Wqkvb, bf16_t* __restrict__ Wob,
                            bf16_t* __restrict__ W1b, bf16_t* __restrict__ W2b,
                            float* __restrict__ bqkv, float* __restrict__ zbias)
{
    int i = blockIdx.x * 256 + threadIdx.x;   // one thread = 4 elements
    if (i < 1048576) { cvt4(src + (size_t)i * 4, Xb + (size_t)i * 4); return; }
    i -= 1048576;
    if (i < 65536)        cvt4(Wq + (size_t)i * 4,            Wqkvb + (size_t)i * 4);
    else if (i < 131072)  cvt4(Wk + (size_t)(i - 65536) * 4,  Wqkvb + (size_t)i * 4);
    else if (i < 196608)  cvt4(Wv + (size_t)(i - 131072) * 4, Wqkvb + (size_t)i * 4);
    else if (i < 262144)  cvt4(Wo + (size_t)(i - 196608) * 4, Wob + (size_t)(i - 196608) * 4);
    else if (i < 524288)  cvt4(W1 + (size_t)(i - 262144) * 4, W1b + (size_t)(i - 262144) * 4);
    else if (i < 786432)  cvt4(W2 + (size_t)(i - 524288) * 4, W2b + (size_t)(i - 524288) * 4);
    else if (i < 786816) {
        int j = i - 786432;   // 0..383 -> 1536 bias floats
        const float* s = (j < 128) ? bq + j * 4 : (j < 256) ? bk + (j - 128) * 4
                                                            : bv + (j - 256) * 4;
        *(float4*)(bqkv + (j & 127) * 4 + (j >> 7) * 512) = *(const float4*)s;
    } else if (i < 786944) {
        int j = i - 786816;   // 0..127 -> 512 zero floats
        *(float4*)(zbias + j * 4) = make_float4(0.f, 0.f, 0.f, 0.f);
    }
}

// ---------------------------------------------------------------------------
// GEMM v2: C[M,N] = A[M,K] @ B[N,K]^T + bias, bf16 in, fp32 accum.
// BM x 128 tile, BK=32, 256 threads. Double-buffered global_load_lds, single
// barrier per iter (DMA for tile k+1 issued right after tile k publishes).
// SPLIT2: gridDim.z==2, each z-half does K/2, writes fp16 partials at
//         Cout + z*M*N; z==1 uses biasz (zeros) so bias applies once.
// EPI: 0 = bias->bf16 ; 1 = bias+GELU->bf16 ; 2 = bias->fp16 partial
// ---------------------------------------------------------------------------
template <int BM, int EPI, bool SPLIT2>
__global__ __launch_bounds__(256)
void gemm_bt(const bf16_t* __restrict__ A, const bf16_t* __restrict__ B,
             const float* __restrict__ bias, const float* __restrict__ biasz,
             void* __restrict__ Cout, int M, int N, int K)
{
    constexpr int MI = BM / 32;
    __shared__ bf16_t sA[2][BM][32];
    __shared__ bf16_t sB[2][128][32];
    bf16_t* sAf = &sA[0][0][0];
    bf16_t* sBf = &sB[0][0][0];

    const int tid  = threadIdx.x;
    const int wave = tid >> 6;
    const int lane = tid & 63;
    const int g    = lane >> 4;
    const int c16  = lane & 15;
    const int wm   = (wave >> 1) * (BM / 2);
    const int wn   = (wave & 1) * 64;
    const int m0   = blockIdx.y * BM;
    const int n0   = blockIdx.x * 128;

    const int zz    = SPLIT2 ? blockIdx.z : 0;
    const int Keff  = SPLIT2 ? (K >> 1) : K;
    const int kbase = zz * Keff;
    const float* bptr = (SPLIT2 && zz) ? biasz : bias;

    const f32x4 fz = {0.f, 0.f, 0.f, 0.f};
    f32x4 acc[MI][4];
#pragma unroll
    for (int i = 0; i < MI; i++)
#pragma unroll
        for (int j = 0; j < 4; j++) acc[i][j] = fz;

    const int srow = tid >> 2;
    const int scol = (tid & 3) * 8;
    const bf16_t* pa = A + (size_t)(m0 + srow) * K + kbase + scol;
    const bf16_t* pb = B + (size_t)(n0 + srow) * K + kbase + scol;

    // prologue: tile 0 -> buf 0
#pragma unroll
    for (int i = 0; i < BM / 64; i++)
        gload16(pa + (size_t)i * 64 * K, sAf + i * 2048 + tid * 8);
#pragma unroll
    for (int i = 0; i < 2; i++)
        gload16(pb + (size_t)i * 64 * K, sBf + i * 2048 + tid * 8);

    const int NK = Keff >> 5;
    for (int kk = 0; kk < NK; ++kk) {
        const int cur = kk & 1;
        __syncthreads();                 // drains DMA for tile kk
        if (kk + 1 < NK) {               // issue tile kk+1 into other buffer
            const int k0 = (kk + 1) * 32;
            bf16_t* dA = sAf + (cur ^ 1) * (BM * 32);
            bf16_t* dB = sBf + (cur ^ 1) * 4096;
#pragma unroll
            for (int i = 0; i < BM / 64; i++)
                gload16(pa + (size_t)i * 64 * K + k0, dA + i * 2048 + tid * 8);
#pragma unroll
            for (int i = 0; i < 2; i++)
                gload16(pb + (size_t)i * 64 * K + k0, dB + i * 2048 + tid * 8);
        }

        bf16x8 af[MI], bfr[4];
#pragma unroll
        for (int i = 0; i < MI; i++)
            af[i] = *(const bf16x8*)&sA[cur][wm + i * 16 + c16][g * 8];
#pragma unroll
        for (int j = 0; j < 4; j++)
            bfr[j] = *(const bf16x8*)&sB[cur][wn + j * 16 + c16][g * 8];
#pragma unroll
        for (int mi = 0; mi < MI; mi++)
#pragma unroll
            for (int ni = 0; ni < 4; ni++)
                acc[mi][ni] = __builtin_amdgcn_mfma_f32_16x16x32_bf16(
                    af[mi], bfr[ni], acc[mi][ni], 0, 0, 0);
    }

    __half* outh = (__half*)Cout + (size_t)zz * M * N;
#pragma unroll
    for (int mi = 0; mi < MI; mi++) {
#pragma unroll
        for (int ni = 0; ni < 4; ni++) {
            const int col = n0 + wn + ni * 16 + c16;
            const float bv = bptr[col];
#pragma unroll
            for (int r = 0; r < 4; r++) {
                const int row = m0 + wm + mi * 16 + g * 4 + r;
                float v = acc[mi][ni][r] + bv;
                if (EPI == 1) v = 0.5f * v * (1.f + erff(v * 0.70710678118654752f));
                if (EPI == 2)
                    outh[(size_t)row * N + col] = (__half)v;
                else
                    ((bf16_t*)Cout)[(size_t)row * N + col] = (bf16_t)v;
            }
        }
    }
}

// ---------------------------------------------------------------------------
// transpose V out of QKV into Vt[bh][64][2048]. Position p within each 64-t
// tile holds token sigma(p) = (p>>5)*32 + ((p>>2)&1)*16 + ((p>>3)&3)*4 + (p&3).
// This ordering makes the S^T C-layout (col=q, row=t-local) line up EXACTLY
// with the B-operand layout of O^T = V^T * P^T, so P never touches LDS.
// ---------------------------------------------------------------------------
__global__ __launch_bounds__(256)
void transpose_v(const bf16_t* __restrict__ qkv, bf16_t* __restrict__ vt)
{
    __shared__ bf16_t st[64][72];
    const int t0 = blockIdx.x * 64;
    const int bh = blockIdx.y;
    const int b = bh >> 3, h = bh & 7;
    const int tid = threadIdx.x;

    for (int c = tid; c < 512; c += 256) {
        int r = c >> 3, cj = (c & 7) * 8;
        const bf16_t* src = qkv + ((size_t)(b * SEQ + t0 + r)) * 1536 + 1024 + h * 64 + cj;
        *(int4*)&st[r][cj] = *(const int4*)src;
    }
    __syncthreads();
    for (int c = tid; c < 512; c += 256) {
        int d = c >> 3, pj = (c & 7) * 8;
        alignas(16) bf16_t tmp[8];
#pragma unroll
        for (int j = 0; j < 8; j++) {
            int p = pj + j;
            int t = ((p >> 5) << 5) + (((p >> 2) & 1) << 4) + (((p >> 3) & 3) << 2) + (p & 3);
            tmp[j] = st[t][d];
        }
        *(int4*)(vt + ((size_t)(bh * 64 + d)) * SEQ + t0 + pj) = *(const int4*)tmp;
    }
}

// ---------------------------------------------------------------------------
// Flash attention v9: P round-trip eliminated (32 KB LDS, zero P LDS traffic).
// grid (SEQ/128, B*H) = (16,32), block 256 (4 waves x 32 q-rows).
// Computes S^T (A=K-frag, B=Q-frag): C-layout col=q'=c16, row=t_local=g*4+r.
// With transpose_v's sigma ordering, the exp-ed values are exactly the
// B-operand fragments of O^T = V^T * P^T -> pure register packing, no sP.
// Row-sum l accumulated per-lane, 2 shuffles at the end (no ones-MFMA).
// K/V double-buffered UNPADDED [64][64], XOR bank-swizzle, DMA staging,
// one barrier/iter. Q pre-scaled by (1/8)*log2(e) -> P = exp2(S).
// waves_per_eu(2,2): grid caps at 2 blocks/CU anyway; pins 256-VGPR budget.
// ---------------------------------------------------------------------------
__global__ __launch_bounds__(256)
__attribute__((amdgpu_waves_per_eu(2, 2)))
void flash_attn(const bf16_t* __restrict__ qkv, const bf16_t* __restrict__ vt,
                bf16_t* __restrict__ ctx)
{
    __shared__ bf16_t sK[2][64][64];    // 16 KB
    __shared__ bf16_t sVt[2][64][64];   // 16 KB

    const int bh = blockIdx.y;
    const int b = bh >> 3, h = bh & 7;
    const int q0 = blockIdx.x * 128;
    const int tid = threadIdx.x;
    const int wave = tid >> 6, lane = tid & 63;
    const int g = lane >> 4, c16 = lane & 15;

    const float qscale = 0.125f * 1.4426950408889634f;   // 1/sqrt(64) * log2(e)
    bf16x8 aq[2][2];   // [qt][ks] B-operand fragments of Q
#pragma unroll
    for (int qt = 0; qt < 2; qt++)
#pragma unroll
        for (int ks = 0; ks < 2; ks++) {
            bf16x8 v = *(const bf16x8*)(qkv +
                ((size_t)(b * SEQ + q0 + wave * 32 + qt * 16 + c16)) * 1536 +
                h * 64 + ks * 32 + g * 8);
#pragma unroll
            for (int j = 0; j < 8; j++) v[j] = (bf16_t)((float)v[j] * qscale);
            aq[qt][ks] = v;
        }

    const f32x4 fz = {0.f, 0.f, 0.f, 0.f};
    f32x4 acc_oT[4][2];   // [dt][qt] : O^T, col=q', row=d_local
#pragma unroll
    for (int dt = 0; dt < 4; dt++)
#pragma unroll
        for (int qt = 0; qt < 2; qt++) acc_oT[dt][qt] = fz;
    float l_acc[2] = {0.f, 0.f};

    const int f0 = tid,        r0 = f0 >> 3, l0 = (f0 & 7) ^ (r0 & 7);
    const int f1 = tid + 256,  r1 = f1 >> 3, l1 = (f1 & 7) ^ (r1 & 7);
    const bf16_t* gK0 = qkv + ((size_t)(b * SEQ + r0)) * 1536 + 512 + h * 64 + l0 * 8;
    const bf16_t* gK1 = qkv + ((size_t)(b * SEQ + r1)) * 1536 + 512 + h * 64 + l1 * 8;
    const bf16_t* gV0 = vt + ((size_t)(bh * 64 + r0)) * SEQ + l0 * 8;
    const bf16_t* gV1 = vt + ((size_t)(bh * 64 + r1)) * SEQ + l1 * 8;
    bf16_t* lK = &sK[0][0][0];
    bf16_t* lV = &sVt[0][0][0];

    gload16(gK0, lK + f0 * 8);
    gload16(gK1, lK + f1 * 8);
    gload16(gV0, lV + f0 * 8);
    gload16(gV1, lV + f1 * 8);

    for (int it = 0; it < 32; ++it) {
        const int cur = it & 1;
        __syncthreads();
        if (it < 31) {
            const size_t kv = (size_t)(it + 1) * 64;
            const int bo = (cur ^ 1) * 4096;
            gload16(gK0 + kv * 1536, lK + bo + f0 * 8);
            gload16(gK1 + kv * 1536, lK + bo + f1 * 8);
            gload16(gV0 + kv,        lV + bo + f0 * 8);
            gload16(gV1 + kv,        lV + bo + f1 * 8);
        }

        // S^T: accs[tt][qt], A = K fragment (m=t_local), B = Q fragment (n=q')
        f32x4 accs[4][2];
#pragma unroll
        for (int tt = 0; tt < 4; tt++)
#pragma unroll
            for (int qt = 0; qt < 2; qt++) accs[tt][qt] = fz;
#pragma unroll
        for (int ks = 0; ks < 2; ks++) {
            const int pc = ((ks * 4 + g) ^ (c16 & 7)) * 8;
#pragma unroll
            for (int tt = 0; tt < 4; tt++) {
                bf16x8 ak = *(const bf16x8*)&sK[cur][tt * 16 + c16][pc];
                accs[tt][0] = __builtin_amdgcn_mfma_f32_16x16x32_bf16(ak, aq[0][ks], accs[tt][0], 0, 0, 0);
                accs[tt][1] = __builtin_amdgcn_mfma_f32_16x16x32_bf16(ak, aq[1][ks], accs[tt][1], 0, 0, 0);
            }
        }

        // P = 2^(S^T) in registers; accumulate row sums; pack B-fragments.
        // Lane (q'=c16, g) holds t-slots tt*16 + g*4 + r; sigma ordering makes
        // pb[qt][kv][j] (k = g*8+j) = accs[kv*2 + (j>>2)][qt][j&3].
#pragma unroll
        for (int tt = 0; tt < 4; tt++)
#pragma unroll
            for (int qt = 0; qt < 2; qt++) {
                float s = 0.f;
#pragma unroll
                for (int r = 0; r < 4; r++) {
                    float p = __builtin_amdgcn_exp2f(accs[tt][qt][r]);
                    accs[tt][qt][r] = p;
                    s += p;
                }
                l_acc[qt] += s;
            }
        bf16x8 pb[2][2];   // [qt][kv]
#pragma unroll
        for (int qt = 0; qt < 2; qt++)
#pragma unroll
            for (int kv = 0; kv < 2; kv++)
#pragma unroll
                for (int j = 0; j < 8; j++)
                    pb[qt][kv][j] = (bf16_t)accs[kv * 2 + (j >> 2)][qt][j & 3];

        // O^T += V^T * P^T  (A = V^T fragment, B = pb; no LDS for P)
#pragma unroll
        for (int kv = 0; kv < 2; kv++) {
            const int pc = ((kv * 4 + g) ^ (c16 & 7)) * 8;
#pragma unroll
            for (int dt = 0; dt < 4; dt++) {
                bf16x8 av = *(const bf16x8*)&sVt[cur][dt * 16 + c16][pc];
                acc_oT[dt][0] = __builtin_amdgcn_mfma_f32_16x16x32_bf16(av, pb[0][kv], acc_oT[dt][0], 0, 0, 0);
                acc_oT[dt][1] = __builtin_amdgcn_mfma_f32_16x16x32_bf16(av, pb[1][kv], acc_oT[dt][1], 0, 0, 0);
            }
        }
    }

    // epilogue: lane (q'=c16, g) holds O[token][d] for d = dt*16 + g*4 + r.
#pragma unroll
    for (int qt = 0; qt < 2; qt++) {
        float l = l_acc[qt];
        l += __shfl_xor(l, 16);
        l += __shfl_xor(l, 32);
        const float inv = 1.0f / l;
        const int token = q0 + wave * 32 + qt * 16 + c16;
        bf16_t* dst = ctx + ((size_t)(b * SEQ + token)) * 512 + h * 64 + g * 4;
#pragma unroll
        for (int dt = 0; dt < 4; dt++) {
            alignas(8) bf16_t o4[4];
#pragma unroll
            for (int r = 0; r < 4; r++) o4[r] = (bf16_t)(acc_oT[dt][qt][r] * inv);
            *(uint2*)(dst + dt * 16) = *(const uint2*)o4;
        }
    }
}

// ---------------------------------------------------------------------------
// out = LayerNorm(a + b + c) * gamma + beta ; a fp32, b/c fp16 partials.
// ---------------------------------------------------------------------------
__global__ __launch_bounds__(256)
void add_ln3(const float* __restrict__ a, const __half* __restrict__ b,
             const __half* __restrict__ c,
             const float* __restrict__ gamma, const float* __restrict__ beta,
             float* __restrict__ outf, bf16_t* __restrict__ outb)
{
    const int row  = blockIdx.x * 4 + (threadIdx.x >> 6);
    const int lane = threadIdx.x & 63;
    const size_t base = (size_t)row * 512 + lane * 8;

    int4 braw = *(const int4*)(b + base);   // 8 halves
    int4 craw = *(const int4*)(c + base);
    const __half* bh = (const __half*)&braw;
    const __half* ch = (const __half*)&craw;

    float v[8];
#pragma unroll
    for (int hh = 0; hh < 2; hh++) {
        float4 av = *(const float4*)(a + base + hh * 4);
        v[hh * 4 + 0] = av.x + (float)bh[hh * 4 + 0] + (float)ch[hh * 4 + 0];
        v[hh * 4 + 1] = av.y + (float)bh[hh * 4 + 1] + (float)ch[hh * 4 + 1];
        v[hh * 4 + 2] = av.z + (float)bh[hh * 4 + 2] + (float)ch[hh * 4 + 2];
        v[hh * 4 + 3] = av.w + (float)bh[hh * 4 + 3] + (float)ch[hh * 4 + 3];
    }

    float s = 0.f;
#pragma unroll
    for (int i = 0; i < 8; i++) s += v[i];
#pragma unroll
    for (int off = 32; off > 0; off >>= 1) s += __shfl_xor(s, off);
    const float mu = s * (1.f / 512.f);

    float q = 0.f;
#pragma unroll
    for (int i = 0; i < 8; i++) { float d = v[i] - mu; q += d * d; }
#pragma unroll
    for (int off = 32; off > 0; off >>= 1) q += __shfl_xor(q, off);
    const float rstd = rsqrtf(q * (1.f / 512.f) + 1e-5f);

    float4 g0 = *(const float4*)(gamma + lane * 8);
    float4 g1 = *(const float4*)(gamma + lane * 8 + 4);
    float4 e0 = *(const float4*)(beta + lane * 8);
    float4 e1 = *(const float4*)(beta + lane * 8 + 4);
    const float gg[8] = {g0.x, g0.y, g0.z, g0.w, g1.x, g1.y, g1.z, g1.w};
    const float ee[8] = {e0.x, e0.y, e0.z, e0.w, e1.x, e1.y, e1.z, e1.w};

    float o[8];
#pragma unroll
    for (int i = 0; i < 8; i++) o[i] = (v[i] - mu) * rstd * gg[i] + ee[i];

    *(float4*)(outf + base)     = make_float4(o[0], o[1], o[2], o[3]);
    *(float4*)(outf + base + 4) = make_float4(o[4], o[5], o[6], o[7]);
    if (outb) {
        alignas(16) bf16_t ob[8];
#pragma unroll
        for (int i = 0; i < 8; i++) ob[i] = (bf16_t)o[i];
        *(int4*)(outb + base) = *(const int4*)ob;
    }
}

// ---------------------------------------------------------------------------
extern "C" void kernel_launch(void* const* d_in, const int* in_sizes, int n_in,
                              void* d_out, int out_size, void* d_ws, size_t ws_size,
                              hipStream_t stream)
{
    const float* src = (const float*)d_in[0];
    const float* Wq  = (const float*)d_in[1];  const float* bq  = (const float*)d_in[2];
    const float* Wk  = (const float*)d_in[3];  const float* bk  = (const float*)d_in[4];
    const float* Wv  = (const float*)d_in[5];  const float* bv  = (const float*)d_in[6];
    const float* Wo  = (const float*)d_in[7];  const float* bo  = (const float*)d_in[8];
    const float* W1  = (const float*)d_in[9];  const float* b1  = (const float*)d_in[10];
    const float* W2  = (const float*)d_in[11]; const float* b2  = (const float*)d_in[12];
    const float* g1  = (const float*)d_in[13]; const float* be1 = (const float*)d_in[14];
    const float* g2  = (const float*)d_in[15]; const float* be2 = (const float*)d_in[16];
    float* out = (float*)d_out;

    char* ws = (char*)d_ws;
    size_t off = 0;
    auto alloc = [&](size_t bytes) -> void* {
        void* p = ws + off;
        off = (off + bytes + 255) & ~(size_t)255;
        return p;
    };

    bf16_t* Xb    = (bf16_t*)alloc((size_t)TOKENS * 512 * 2);
    bf16_t* Wqkvb = (bf16_t*)alloc((size_t)1536 * 512 * 2);
    bf16_t* Wob   = (bf16_t*)alloc((size_t)512 * 512 * 2);
    bf16_t* W1b   = (bf16_t*)alloc((size_t)2048 * 512 * 2);
    bf16_t* W2b   = (bf16_t*)alloc((size_t)512 * 2048 * 2);
    float*  bqkv  = (float*)alloc(1536 * 4);
    float*  zbias = (float*)alloc(512 * 4);
    bf16_t* QKV   = (bf16_t*)alloc((size_t)TOKENS * 1536 * 2);  // contiguous with Vt
    bf16_t* Vt    = (bf16_t*)alloc((size_t)32 * 64 * SEQ * 2);
    bf16_t* CTX   = (bf16_t*)alloc((size_t)TOKENS * 512 * 2);
    __half* ATTa  = (__half*)alloc((size_t)TOKENS * 512 * 2);   // contiguous with ATTb
    __half* ATTb  = (__half*)alloc((size_t)TOKENS * 512 * 2);
    float*  X1    = (float*)alloc((size_t)TOKENS * 512 * 4);
    bf16_t* X1b   = (bf16_t*)alloc((size_t)TOKENS * 512 * 2);

    bf16_t* H    = QKV;    // alias: QKV+Vt (33.55 MB exactly) dead after flash
    __half* FFNa = ATTa;   // alias: ATTa/ATTb dead after ln1 (contiguous pair)
    __half* FFNb = ATTb;

    cvt_weights<<<7170, 256, 0, stream>>>(src, Wq, Wk, Wv, Wo, W1, W2, bq, bk, bv,
                                          Xb, Wqkvb, Wob, W1b, W2b, bqkv, zbias);

    // fused QKV projection
    gemm_bt<128, 0, false><<<dim3(12, 64), 256, 0, stream>>>(
        Xb, Wqkvb, bqkv, zbias, QKV, TOKENS, 1536, 512);

    transpose_v<<<dim3(32, 32), 256, 0, stream>>>(QKV, Vt);
    flash_attn<<<dim3(16, 32), 256, 0, stream>>>(QKV, Vt, CTX);

    // Wo projection, split-K=2 -> fp16 partials ATTa/ATTb
    gemm_bt<64, 2, true><<<dim3(4, 128, 2), 256, 0, stream>>>(
        CTX, Wob, bo, zbias, ATTa, TOKENS, 512, 512);

    add_ln3<<<2048, 256, 0, stream>>>(src, ATTa, ATTb, g1, be1, X1, X1b);

    gemm_bt<128, 1, false><<<dim3(16, 64), 256, 0, stream>>>(
        X1b, W1b, b1, zbias, H, TOKENS, 2048, 512);

    // W2, split-K=2 -> fp16 partials FFNa/FFNb
    gemm_bt<64, 2, true><<<dim3(4, 128, 2), 256, 0, stream>>>(
        H, W2b, b2, zbias, FFNa, TOKENS, 512, 2048);

    add_ln3<<<2048, 256, 0, stream>>>(X1, FFNa, FFNb, g2, be2, out, nullptr);
}

// Round 11
// 279.236 us; speedup vs baseline: 1.6514x; 1.0073x over previous
//
#include <hip/hip_runtime.h>
#include <hip/hip_bf16.h>
#include <hip/hip_fp16.h>
#include <math.h>

// ---------------------------------------------------------------------------
typedef __bf16 bf16_t;
typedef __bf16 bf16x8 __attribute__((ext_vector_type(8)));
typedef __bf16 bf16x2 __attribute__((ext_vector_type(2)));
typedef float  f32x4  __attribute__((ext_vector_type(4)));

#define D_MODEL 512
#define NHEAD   8
#define HD      64
#define D_FF    2048
#define TOKENS  8192   // 4 * 2048
#define SEQ     2048
#define BATCH   4

// async global->LDS, 16B per lane; LDS dest = wave-uniform base + lane*16
__device__ __forceinline__ void gload16(const bf16_t* g, bf16_t* l)
{
    __builtin_amdgcn_global_load_lds(
        (const __attribute__((address_space(1))) void*)g,
        (__attribute__((address_space(3))) void*)l,
        16, 0, 0);
}

__device__ __forceinline__ void cvt4(const float* s, bf16_t* d)
{
    float4 v = *(const float4*)s;
    alignas(8) bf16_t t[4] = {(bf16_t)v.x, (bf16_t)v.y, (bf16_t)v.z, (bf16_t)v.w};
    *(uint2*)d = *(const uint2*)t;
}

// ---------------------------------------------------------------------------
// src + all weight conversions + bias concat + zero-bias fill in ONE kernel.
// ---------------------------------------------------------------------------
__global__ void cvt_weights(const float* __restrict__ src,
                            const float* __restrict__ Wq, const float* __restrict__ Wk,
                            const float* __restrict__ Wv, const float* __restrict__ Wo,
                            const float* __restrict__ W1, const float* __restrict__ W2,
                            const float* __restrict__ bq, const float* __restrict__ bk,
                            const float* __restrict__ bv,
                            bf16_t* __restrict__ Xb,
                            bf16_t* __restrict__ Wqkvb, bf16_t* __restrict__ Wob,
                            bf16_t* __restrict__ W1b, bf16_t* __restrict__ W2b,
                            float* __restrict__ bqkv, float* __restrict__ zbias)
{
    int i = blockIdx.x * 256 + threadIdx.x;   // one thread = 4 elements
    if (i < 1048576) { cvt4(src + (size_t)i * 4, Xb + (size_t)i * 4); return; }
    i -= 1048576;
    if (i < 65536)        cvt4(Wq + (size_t)i * 4,            Wqkvb + (size_t)i * 4);
    else if (i < 131072)  cvt4(Wk + (size_t)(i - 65536) * 4,  Wqkvb + (size_t)i * 4);
    else if (i < 196608)  cvt4(Wv + (size_t)(i - 131072) * 4, Wqkvb + (size_t)i * 4);
    else if (i < 262144)  cvt4(Wo + (size_t)(i - 196608) * 4, Wob + (size_t)(i - 196608) * 4);
    else if (i < 524288)  cvt4(W1 + (size_t)(i - 262144) * 4, W1b + (size_t)(i - 262144) * 4);
    else if (i < 786432)  cvt4(W2 + (size_t)(i - 524288) * 4, W2b + (size_t)(i - 524288) * 4);
    else if (i < 786816) {
        int j = i - 786432;   // 0..383 -> 1536 bias floats
        const float* s = (j < 128) ? bq + j * 4 : (j < 256) ? bk + (j - 128) * 4
                                                            : bv + (j - 256) * 4;
        *(float4*)(bqkv + (j & 127) * 4 + (j >> 7) * 512) = *(const float4*)s;
    } else if (i < 786944) {
        int j = i - 786816;   // 0..127 -> 512 zero floats
        *(float4*)(zbias + j * 4) = make_float4(0.f, 0.f, 0.f, 0.f);
    }
}

// ---------------------------------------------------------------------------
// GEMM v3: C[M,N] = A[M,K] @ B[N,K]^T + bias, bf16 in, fp32 accum.
// BM x 128 tile, 256 threads. BK=64 SUPER-TILES (2 x 32 sub-tiles),
// double-buffered, ONE barrier per super-iter: 2x the compute per barrier
// interval vs BK=32 and half the barrier count -- the K=512 short-K regime
// was latency-bound at ~150 cyc compute vs ~700 cyc DMA per interval
// (R10: FFN1 MfmaUtil 7.9%, 210 TF).
// LDS unpadded [BM][64] / [128][64] with flash-v8 XOR chunk swizzle
// (phys16B = logical ^ (row&7); measured 0 bank conflicts). Staging is pure
// global_load_lds DMA -- zero data VGPRs, no spill risk.
// SPLIT2: gridDim.z==2, each z-half does K/2, writes fp16 partials at
//         Cout + z*M*N; z==1 uses biasz (zeros) so bias applies once.
// EPI: 0 = bias->bf16 ; 1 = bias+GELU->bf16 ; 2 = bias->fp16 partial
// ---------------------------------------------------------------------------
template <int BM, int EPI, bool SPLIT2>
__global__ __launch_bounds__(256)
void gemm_bt(const bf16_t* __restrict__ A, const bf16_t* __restrict__ B,
             const float* __restrict__ bias, const float* __restrict__ biasz,
             void* __restrict__ Cout, int M, int N, int K)
{
    constexpr int MI = BM / 32;     // m-fragments per wave
    constexpr int NA = BM / 32;     // A DMA issues per stage (BM*8 chunks / 256)
    __shared__ bf16_t sA[2][BM][64];   // 16/32 KB
    __shared__ bf16_t sB[2][128][64];  // 32 KB
    bf16_t* sAf = &sA[0][0][0];
    bf16_t* sBf = &sB[0][0][0];

    const int tid  = threadIdx.x;
    const int wave = tid >> 6;
    const int lane = tid & 63;
    const int g    = lane >> 4;
    const int c16  = lane & 15;
    const int wm   = (wave >> 1) * (BM / 2);
    const int wn   = (wave & 1) * 64;
    const int m0   = blockIdx.y * BM;
    const int n0   = blockIdx.x * 128;

    const int zz    = SPLIT2 ? blockIdx.z : 0;
    const int Keff  = SPLIT2 ? (K >> 1) : K;
    const int kbase = zz * Keff;
    const float* bptr = (SPLIT2 && zz) ? biasz : bias;

    const f32x4 fz = {0.f, 0.f, 0.f, 0.f};
    f32x4 acc[MI][4];
#pragma unroll
    for (int i = 0; i < MI; i++)
#pragma unroll
        for (int j = 0; j < 4; j++) acc[i][j] = fz;

    // DMA staging map: flat 16B-chunk f = issue*256 + tid; row = f>>3,
    // physical chunk p = f&7 receives LOGICAL chunk l = p ^ (row&7).
    const bf16_t* gA[NA]; int fa[NA];
#pragma unroll
    for (int i = 0; i < NA; i++) {
        const int f = i * 256 + tid, row = f >> 3, l = (f & 7) ^ (row & 7);
        fa[i] = f;
        gA[i] = A + (size_t)(m0 + row) * K + kbase + l * 8;
    }
    const bf16_t* gB[4]; int fb[4];
#pragma unroll
    for (int i = 0; i < 4; i++) {
        const int f = i * 256 + tid, row = f >> 3, l = (f & 7) ^ (row & 7);
        fb[i] = f;
        gB[i] = B + (size_t)(n0 + row) * K + kbase + l * 8;
    }

    // prologue: super-tile 0 -> buf 0
#pragma unroll
    for (int i = 0; i < NA; i++) gload16(gA[i], sAf + fa[i] * 8);
#pragma unroll
    for (int i = 0; i < 4; i++)  gload16(gB[i], sBf + fb[i] * 8);

    const int NS = Keff >> 6;
    for (int s = 0; s < NS; ++s) {
        const int cur = s & 1;
        __syncthreads();                 // drains DMA for super-tile s
        if (s + 1 < NS) {                // issue super-tile s+1 into other buf
            const int ko = (s + 1) * 64;
            bf16_t* dA = sAf + (cur ^ 1) * (BM * 64);
            bf16_t* dB = sBf + (cur ^ 1) * 8192;
#pragma unroll
            for (int i = 0; i < NA; i++) gload16(gA[i] + ko, dA + fa[i] * 8);
#pragma unroll
            for (int i = 0; i < 4; i++)  gload16(gB[i] + ko, dB + fb[i] * 8);
        }

        // compute 2 sub-tiles (k = sub*32 .. sub*32+31); fragment row&7 ==
        // c16&7, so read chunk = (sub*4+g) ^ (c16&7)  -> conflict-free.
#pragma unroll
        for (int sub = 0; sub < 2; ++sub) {
            const int ck = (((sub * 4 + g) ^ (c16 & 7))) * 8;
            bf16x8 af[MI], bfr[4];
#pragma unroll
            for (int i = 0; i < MI; i++)
                af[i] = *(const bf16x8*)&sA[cur][wm + i * 16 + c16][ck];
#pragma unroll
            for (int j = 0; j < 4; j++)
                bfr[j] = *(const bf16x8*)&sB[cur][wn + j * 16 + c16][ck];
#pragma unroll
            for (int mi = 0; mi < MI; mi++)
#pragma unroll
                for (int ni = 0; ni < 4; ni++)
                    acc[mi][ni] = __builtin_amdgcn_mfma_f32_16x16x32_bf16(
                        af[mi], bfr[ni], acc[mi][ni], 0, 0, 0);
        }
    }

    __half* outh = (__half*)Cout + (size_t)zz * M * N;
#pragma unroll
    for (int mi = 0; mi < MI; mi++) {
#pragma unroll
        for (int ni = 0; ni < 4; ni++) {
            const int col = n0 + wn + ni * 16 + c16;
            const float bv = bptr[col];
#pragma unroll
            for (int r = 0; r < 4; r++) {
                const int row = m0 + wm + mi * 16 + g * 4 + r;
                float v = acc[mi][ni][r] + bv;
                if (EPI == 1) v = 0.5f * v * (1.f + erff(v * 0.70710678118654752f));
                if (EPI == 2)
                    outh[(size_t)row * N + col] = (__half)v;
                else
                    ((bf16_t*)Cout)[(size_t)row * N + col] = (bf16_t)v;
            }
        }
    }
}

// ---------------------------------------------------------------------------
// transpose V out of QKV into Vt[bh][64][2048]. Position p within each 64-t
// tile holds token sigma(p) = (p>>5)*32 + ((p>>2)&1)*16 + ((p>>3)&3)*4 + (p&3).
// This ordering makes the S^T C-layout (col=q, row=t-local) line up EXACTLY
// with the B-operand layout of O^T = V^T * P^T, so P never touches LDS.
// ---------------------------------------------------------------------------
__global__ __launch_bounds__(256)
void transpose_v(const bf16_t* __restrict__ qkv, bf16_t* __restrict__ vt)
{
    __shared__ bf16_t st[64][72];
    const int t0 = blockIdx.x * 64;
    const int bh = blockIdx.y;
    const int b = bh >> 3, h = bh & 7;
    const int tid = threadIdx.x;

    for (int c = tid; c < 512; c += 256) {
        int r = c >> 3, cj = (c & 7) * 8;
        const bf16_t* src = qkv + ((size_t)(b * SEQ + t0 + r)) * 1536 + 1024 + h * 64 + cj;
        *(int4*)&st[r][cj] = *(const int4*)src;
    }
    __syncthreads();
    for (int c = tid; c < 512; c += 256) {
        int d = c >> 3, pj = (c & 7) * 8;
        alignas(16) bf16_t tmp[8];
#pragma unroll
        for (int j = 0; j < 8; j++) {
            int p = pj + j;
            int t = ((p >> 5) << 5) + (((p >> 2) & 1) << 4) + (((p >> 3) & 3) << 2) + (p & 3);
            tmp[j] = st[t][d];
        }
        *(int4*)(vt + ((size_t)(bh * 64 + d)) * SEQ + t0 + pj) = *(const int4*)tmp;
    }
}

// ---------------------------------------------------------------------------
// Flash attention v9 (unchanged from R10): P round-trip eliminated.
// grid (SEQ/128, B*H) = (16,32), block 256 (4 waves x 32 q-rows).
// S^T via A=K-frag, B=Q-frag; exp in registers; O^T = V^T * P^T with P as
// packed register B-fragments (transpose_v's sigma ordering). 32 KB LDS,
// XOR bank-swizzle, DMA staging, one barrier/iter. l per-lane + 2 shuffles.
// ---------------------------------------------------------------------------
__global__ __launch_bounds__(256)
__attribute__((amdgpu_waves_per_eu(2, 2)))
void flash_attn(const bf16_t* __restrict__ qkv, const bf16_t* __restrict__ vt,
                bf16_t* __restrict__ ctx)
{
    __shared__ bf16_t sK[2][64][64];    // 16 KB
    __shared__ bf16_t sVt[2][64][64];   // 16 KB

    const int bh = blockIdx.y;
    const int b = bh >> 3, h = bh & 7;
    const int q0 = blockIdx.x * 128;
    const int tid = threadIdx.x;
    const int wave = tid >> 6, lane = tid & 63;
    const int g = lane >> 4, c16 = lane & 15;

    const float qscale = 0.125f * 1.4426950408889634f;   // 1/sqrt(64) * log2(e)
    bf16x8 aq[2][2];   // [qt][ks] B-operand fragments of Q
#pragma unroll
    for (int qt = 0; qt < 2; qt++)
#pragma unroll
        for (int ks = 0; ks < 2; ks++) {
            bf16x8 v = *(const bf16x8*)(qkv +
                ((size_t)(b * SEQ + q0 + wave * 32 + qt * 16 + c16)) * 1536 +
                h * 64 + ks * 32 + g * 8);
#pragma unroll
            for (int j = 0; j < 8; j++) v[j] = (bf16_t)((float)v[j] * qscale);
            aq[qt][ks] = v;
        }

    const f32x4 fz = {0.f, 0.f, 0.f, 0.f};
    f32x4 acc_oT[4][2];   // [dt][qt] : O^T, col=q', row=d_local
#pragma unroll
    for (int dt = 0; dt < 4; dt++)
#pragma unroll
        for (int qt = 0; qt < 2; qt++) acc_oT[dt][qt] = fz;
    float l_acc[2] = {0.f, 0.f};

    const int f0 = tid,        r0 = f0 >> 3, l0 = (f0 & 7) ^ (r0 & 7);
    const int f1 = tid + 256,  r1 = f1 >> 3, l1 = (f1 & 7) ^ (r1 & 7);
    const bf16_t* gK0 = qkv + ((size_t)(b * SEQ + r0)) * 1536 + 512 + h * 64 + l0 * 8;
    const bf16_t* gK1 = qkv + ((size_t)(b * SEQ + r1)) * 1536 + 512 + h * 64 + l1 * 8;
    const bf16_t* gV0 = vt + ((size_t)(bh * 64 + r0)) * SEQ + l0 * 8;
    const bf16_t* gV1 = vt + ((size_t)(bh * 64 + r1)) * SEQ + l1 * 8;
    bf16_t* lK = &sK[0][0][0];
    bf16_t* lV = &sVt[0][0][0];

    gload16(gK0, lK + f0 * 8);
    gload16(gK1, lK + f1 * 8);
    gload16(gV0, lV + f0 * 8);
    gload16(gV1, lV + f1 * 8);

    for (int it = 0; it < 32; ++it) {
        const int cur = it & 1;
        __syncthreads();
        if (it < 31) {
            const size_t kv = (size_t)(it + 1) * 64;
            const int bo = (cur ^ 1) * 4096;
            gload16(gK0 + kv * 1536, lK + bo + f0 * 8);
            gload16(gK1 + kv * 1536, lK + bo + f1 * 8);
            gload16(gV0 + kv,        lV + bo + f0 * 8);
            gload16(gV1 + kv,        lV + bo + f1 * 8);
        }

        // S^T: accs[tt][qt], A = K fragment (m=t_local), B = Q fragment (n=q')
        f32x4 accs[4][2];
#pragma unroll
        for (int tt = 0; tt < 4; tt++)
#pragma unroll
            for (int qt = 0; qt < 2; qt++) accs[tt][qt] = fz;
#pragma unroll
        for (int ks = 0; ks < 2; ks++) {
            const int pc = ((ks * 4 + g) ^ (c16 & 7)) * 8;
#pragma unroll
            for (int tt = 0; tt < 4; tt++) {
                bf16x8 ak = *(const bf16x8*)&sK[cur][tt * 16 + c16][pc];
                accs[tt][0] = __builtin_amdgcn_mfma_f32_16x16x32_bf16(ak, aq[0][ks], accs[tt][0], 0, 0, 0);
                accs[tt][1] = __builtin_amdgcn_mfma_f32_16x16x32_bf16(ak, aq[1][ks], accs[tt][1], 0, 0, 0);
            }
        }

        // P = 2^(S^T) in registers; accumulate row sums; pack B-fragments.
#pragma unroll
        for (int tt = 0; tt < 4; tt++)
#pragma unroll
            for (int qt = 0; qt < 2; qt++) {
                float s = 0.f;
#pragma unroll
                for (int r = 0; r < 4; r++) {
                    float p = __builtin_amdgcn_exp2f(accs[tt][qt][r]);
                    accs[tt][qt][r] = p;
                    s += p;
                }
                l_acc[qt] += s;
            }
        bf16x8 pb[2][2];   // [qt][kv]
#pragma unroll
        for (int qt = 0; qt < 2; qt++)
#pragma unroll
            for (int kv = 0; kv < 2; kv++)
#pragma unroll
                for (int j = 0; j < 8; j++)
                    pb[qt][kv][j] = (bf16_t)accs[kv * 2 + (j >> 2)][qt][j & 3];

        // O^T += V^T * P^T  (A = V^T fragment, B = pb; no LDS for P)
#pragma unroll
        for (int kv = 0; kv < 2; kv++) {
            const int pc = ((kv * 4 + g) ^ (c16 & 7)) * 8;
#pragma unroll
            for (int dt = 0; dt < 4; dt++) {
                bf16x8 av = *(const bf16x8*)&sVt[cur][dt * 16 + c16][pc];
                acc_oT[dt][0] = __builtin_amdgcn_mfma_f32_16x16x32_bf16(av, pb[0][kv], acc_oT[dt][0], 0, 0, 0);
                acc_oT[dt][1] = __builtin_amdgcn_mfma_f32_16x16x32_bf16(av, pb[1][kv], acc_oT[dt][1], 0, 0, 0);
            }
        }
    }

    // epilogue: lane (q'=c16, g) holds O[token][d] for d = dt*16 + g*4 + r.
#pragma unroll
    for (int qt = 0; qt < 2; qt++) {
        float l = l_acc[qt];
        l += __shfl_xor(l, 16);
        l += __shfl_xor(l, 32);
        const float inv = 1.0f / l;
        const int token = q0 + wave * 32 + qt * 16 + c16;
        bf16_t* dst = ctx + ((size_t)(b * SEQ + token)) * 512 + h * 64 + g * 4;
#pragma unroll
        for (int dt = 0; dt < 4; dt++) {
            alignas(8) bf16_t o4[4];
#pragma unroll
            for (int r = 0; r < 4; r++) o4[r] = (bf16_t)(acc_oT[dt][qt][r] * inv);
            *(uint2*)(dst + dt * 16) = *(const uint2*)o4;
        }
    }
}

// ---------------------------------------------------------------------------
// out = LayerNorm(a + b + c) * gamma + beta ; a fp32, b/c fp16 partials.
// ---------------------------------------------------------------------------
__global__ __launch_bounds__(256)
void add_ln3(const float* __restrict__ a, const __half* __restrict__ b,
             const __half* __restrict__ c,
             const float* __restrict__ gamma, const float* __restrict__ beta,
             float* __restrict__ outf, bf16_t* __restrict__ outb)
{
    const int row  = blockIdx.x * 4 + (threadIdx.x >> 6);
    const int lane = threadIdx.x & 63;
    const size_t base = (size_t)row * 512 + lane * 8;

    int4 braw = *(const int4*)(b + base);   // 8 halves
    int4 craw = *(const int4*)(c + base);
    const __half* bh = (const __half*)&braw;
    const __half* ch = (const __half*)&craw;

    float v[8];
#pragma unroll
    for (int hh = 0; hh < 2; hh++) {
        float4 av = *(const float4*)(a + base + hh * 4);
        v[hh * 4 + 0] = av.x + (float)bh[hh * 4 + 0] + (float)ch[hh * 4 + 0];
        v[hh * 4 + 1] = av.y + (float)bh[hh * 4 + 1] + (float)ch[hh * 4 + 1];
        v[hh * 4 + 2] = av.z + (float)bh[hh * 4 + 2] + (float)ch[hh * 4 + 2];
        v[hh * 4 + 3] = av.w + (float)bh[hh * 4 + 3] + (float)ch[hh * 4 + 3];
    }

    float s = 0.f;
#pragma unroll
    for (int i = 0; i < 8; i++) s += v[i];
#pragma unroll
    for (int off = 32; off > 0; off >>= 1) s += __shfl_xor(s, off);
    const float mu = s * (1.f / 512.f);

    float q = 0.f;
#pragma unroll
    for (int i = 0; i < 8; i++) { float d = v[i] - mu; q += d * d; }
#pragma unroll
    for (int off = 32; off > 0; off >>= 1) q += __shfl_xor(q, off);
    const float rstd = rsqrtf(q * (1.f / 512.f) + 1e-5f);

    float4 g0 = *(const float4*)(gamma + lane * 8);
    float4 g1 = *(const float4*)(gamma + lane * 8 + 4);
    float4 e0 = *(const float4*)(beta + lane * 8);
    float4 e1 = *(const float4*)(beta + lane * 8 + 4);
    const float gg[8] = {g0.x, g0.y, g0.z, g0.w, g1.x, g1.y, g1.z, g1.w};
    const float ee[8] = {e0.x, e0.y, e0.z, e0.w, e1.x, e1.y, e1.z, e1.w};

    float o[8];
#pragma unroll
    for (int i = 0; i < 8; i++) o[i] = (v[i] - mu) * rstd * gg[i] + ee[i];

    *(float4*)(outf + base)     = make_float4(o[0], o[1], o[2], o[3]);
    *(float4*)(outf + base + 4) = make_float4(o[4], o[5], o[6], o[7]);
    if (outb) {
        alignas(16) bf16_t ob[8];
#pragma unroll
        for (int i = 0; i < 8; i++) ob[i] = (bf16_t)o[i];
        *(int4*)(outb + base) = *(const int4*)ob;
    }
}

// ---------------------------------------------------------------------------
extern "C" void kernel_launch(void* const* d_in, const int* in_sizes, int n_in,
                              void* d_out, int out_size, void* d_ws, size_t ws_size,
                              hipStream_t stream)
{
    const float* src = (const float*)d_in[0];
    const float* Wq  = (const float*)d_in[1];  const float* bq  = (const float*)d_in[2];
    const float* Wk  = (const float*)d_in[3];  const float* bk  = (const float*)d_in[4];
    const float* Wv  = (const float*)d_in[5];  const float* bv  = (const float*)d_in[6];
    const float* Wo  = (const float*)d_in[7];  const float* bo  = (const float*)d_in[8];
    const float* W1  = (const float*)d_in[9];  const float* b1  = (const float*)d_in[10];
    const float* W2  = (const float*)d_in[11]; const float* b2  = (const float*)d_in[12];
    const float* g1  = (const float*)d_in[13]; const float* be1 = (const float*)d_in[14];
    const float* g2  = (const float*)d_in[15]; const float* be2 = (const float*)d_in[16];
    float* out = (float*)d_out;

    char* ws = (char*)d_ws;
    size_t off = 0;
    auto alloc = [&](size_t bytes) -> void* {
        void* p = ws + off;
        off = (off + bytes + 255) & ~(size_t)255;
        return p;
    };

    bf16_t* Xb    = (bf16_t*)alloc((size_t)TOKENS * 512 * 2);
    bf16_t* Wqkvb = (bf16_t*)alloc((size_t)1536 * 512 * 2);
    bf16_t* Wob   = (bf16_t*)alloc((size_t)512 * 512 * 2);
    bf16_t* W1b   = (bf16_t*)alloc((size_t)2048 * 512 * 2);
    bf16_t* W2b   = (bf16_t*)alloc((size_t)512 * 2048 * 2);
    float*  bqkv  = (float*)alloc(1536 * 4);
    float*  zbias = (float*)alloc(512 * 4);
    bf16_t* QKV   = (bf16_t*)alloc((size_t)TOKENS * 1536 * 2);  // contiguous with Vt
    bf16_t* Vt    = (bf16_t*)alloc((size_t)32 * 64 * SEQ * 2);
    bf16_t* CTX   = (bf16_t*)alloc((size_t)TOKENS * 512 * 2);
    __half* ATTa  = (__half*)alloc((size_t)TOKENS * 512 * 2);   // contiguous with ATTb
    __half* ATTb  = (__half*)alloc((size_t)TOKENS * 512 * 2);
    float*  X1    = (float*)alloc((size_t)TOKENS * 512 * 4);
    bf16_t* X1b   = (bf16_t*)alloc((size_t)TOKENS * 512 * 2);

    bf16_t* H    = QKV;    // alias: QKV+Vt (33.55 MB exactly) dead after flash
    __half* FFNa = ATTa;   // alias: ATTa/ATTb dead after ln1 (contiguous pair)
    __half* FFNb = ATTb;

    cvt_weights<<<7170, 256, 0, stream>>>(src, Wq, Wk, Wv, Wo, W1, W2, bq, bk, bv,
                                          Xb, Wqkvb, Wob, W1b, W2b, bqkv, zbias);

    // fused QKV projection
    gemm_bt<128, 0, false><<<dim3(12, 64), 256, 0, stream>>>(
        Xb, Wqkvb, bqkv, zbias, QKV, TOKENS, 1536, 512);

    transpose_v<<<dim3(32, 32), 256, 0, stream>>>(QKV, Vt);
    flash_attn<<<dim3(16, 32), 256, 0, stream>>>(QKV, Vt, CTX);

    // Wo projection, split-K=2 -> fp16 partials ATTa/ATTb
    gemm_bt<64, 2, true><<<dim3(4, 128, 2), 256, 0, stream>>>(
        CTX, Wob, bo, zbias, ATTa, TOKENS, 512, 512);

    add_ln3<<<2048, 256, 0, stream>>>(src, ATTa, ATTb, g1, be1, X1, X1b);

    gemm_bt<128, 1, false><<<dim3(16, 64), 256, 0, stream>>>(
        X1b, W1b, b1, zbias, H, TOKENS, 2048, 512);

    // W2, split-K=2 -> fp16 partials FFNa/FFNb
    gemm_bt<64, 2, true><<<dim3(4, 128, 2), 256, 0, stream>>>(
        H, W2b, b2, zbias, FFNa, TOKENS, 512, 2048);

    add_ln3<<<2048, 256, 0, stream>>>(X1, FFNa, FFNb, g2, be2, out, nullptr);
}